// Round 4
// baseline (772.721 us; speedup 1.0000x reference)
//
#include <hip/hip_runtime.h>
#include <hip/hip_bf16.h>
#include <math.h>

#define DIM 384
#define HEADS 6
#define NN 3136
#define BB 16
#define BH (BB*HEADS)
#define HP 58
#define NP (HP*HP)   // 3364 padded image

typedef __attribute__((ext_vector_type(8))) short short8;
typedef __attribute__((ext_vector_type(4))) short short4v;
typedef __attribute__((ext_vector_type(4))) float f32x4;

__device__ __forceinline__ float bf2f(unsigned short u) {
    union { unsigned int i; float f; } v; v.i = ((unsigned int)u) << 16; return v.f;
}
__device__ __forceinline__ unsigned short f2bf(float f) {
    union { float f; unsigned int i; } v; v.f = f;
    unsigned int r = v.i + 0x7fffu + ((v.i >> 16) & 1u);
    return (unsigned short)(r >> 16);
}
__device__ __forceinline__ void glds16(const unsigned short* g, void* l) {
    __builtin_amdgcn_global_load_lds(
        (const __attribute__((address_space(1))) unsigned int*)g,
        (__attribute__((address_space(3))) unsigned int*)l, 16, 0, 0);
}

// ---------------- weight conversion / rearrange ----------------
__global__ void kw_convert(const float* __restrict__ qkv_w, const float* __restrict__ proj_w,
                           const float* __restrict__ conv_w,
                           unsigned short* __restrict__ Wq, unsigned short* __restrict__ Wp,
                           unsigned short* __restrict__ Wc) {
    int tid = blockIdx.x * 256 + threadIdx.x;
    int stride = gridDim.x * 256;
    for (int i = tid; i < 3*DIM*DIM; i += stride) Wq[i] = f2bf(qkv_w[i]);
    for (int i = tid; i < DIM*DIM; i += stride) Wp[i] = f2bf(proj_w[i]);
    for (int i = tid; i < DIM*DIM*9; i += stride) {
        // dst layout: [o][tap][i]   src: (o, i, ky, kx) -> (o*384+i)*9 + tap
        int ii = i % DIM; int rest = i / DIM; int tap = rest % 9; int o = rest / 9;
        Wc[i] = f2bf(conv_w[(size_t)(o*DIM + ii)*9 + tap]);
    }
}

// ---------------- positional encoding table P[n][c] ----------------
__global__ void k_pos(const float* __restrict__ pos_w, const float* __restrict__ pos_b,
                      float* __restrict__ P) {
    int n = blockIdx.x; int h = n / 56, w = n % 56;
    __shared__ float feat[64];
    int t = threadIdx.x;
    if (t < 64) {
        int axis = t >> 5;      // 0 = y (h), 1 = x (w)
        int k = t & 31; int i = k >> 1;
        float e = (float)((axis ? w : h) + 1) / 56.000001f * 6.28318530717958647692f;
        float arg = e / powf(10000.0f, (float)i / 16.0f);
        feat[t] = (k & 1) ? cosf(arg) : sinf(arg);
    }
    __syncthreads();
    for (int c = t; c < DIM; c += blockDim.x) {
        float s = pos_b[c];
        #pragma unroll 8
        for (int k = 0; k < 64; k++) s += feat[k] * pos_w[c*64 + k];
        P[(size_t)n*DIM + c] = s;
    }
}

// ---------------- fused transpose + pos add + layernorm ----------------
// Block: 32 n-rows x 384 c for one b. XT fp32 (for proj residual) + XN bf16.
__global__ __launch_bounds__(256) void k_tln(const float* __restrict__ x, const float* __restrict__ P,
                                             const float* __restrict__ g, const float* __restrict__ be,
                                             float* __restrict__ XT, unsigned short* __restrict__ XN) {
    __shared__ float tile[32][388];
    int blk = blockIdx.x;
    int b = blk / 98, nt = blk % 98;
    int n0 = nt*32;
    int t = threadIdx.x;
    // phase 1: load x[b][c][n0..n0+32) and transpose into tile[n][c]
    #pragma unroll
    for (int it = 0; it < 12; it++) {
        int task = it*256 + t;
        int c = task >> 3, seg = task & 7;
        float4 v = *reinterpret_cast<const float4*>(x + ((size_t)(b*DIM + c))*NN + n0 + seg*4);
        tile[seg*4+0][c] = v.x; tile[seg*4+1][c] = v.y;
        tile[seg*4+2][c] = v.z; tile[seg*4+3][c] = v.w;
    }
    __syncthreads();
    // phase 2: per-row LN (8 threads/row), xp kept in registers
    int row = t >> 3, sub = t & 7;
    int n = n0 + row;
    f32x4 xp[12];
    float s = 0.f;
    #pragma unroll
    for (int k = 0; k < 12; k++) {
        int c0 = (k*8 + sub)*4;
        float4 tv = *reinterpret_cast<float4*>(&tile[row][c0]);
        float4 pv = *reinterpret_cast<const float4*>(P + (size_t)n*DIM + c0);
        f32x4 xv = {tv.x+pv.x, tv.y+pv.y, tv.z+pv.z, tv.w+pv.w};
        xp[k] = xv;
        s += xv[0]+xv[1]+xv[2]+xv[3];
        *reinterpret_cast<float4*>(XT + ((size_t)(b*NN + n))*DIM + c0) = *(float4*)&xv;
    }
    s += __shfl_xor(s, 1, 64); s += __shfl_xor(s, 2, 64); s += __shfl_xor(s, 4, 64);
    float mean = s * (1.0f/384.0f);
    float sq = 0.f;
    #pragma unroll
    for (int k = 0; k < 12; k++) {
        #pragma unroll
        for (int e = 0; e < 4; e++) { float d = xp[k][e]-mean; sq += d*d; }
    }
    sq += __shfl_xor(sq, 1, 64); sq += __shfl_xor(sq, 2, 64); sq += __shfl_xor(sq, 4, 64);
    float rs = rsqrtf(sq * (1.0f/384.0f) + 1e-6f);
    #pragma unroll
    for (int k = 0; k < 12; k++) {
        int c0 = (k*8 + sub)*4;
        unsigned short pk[4];
        #pragma unroll
        for (int e = 0; e < 4; e++)
            pk[e] = f2bf((xp[k][e]-mean)*rs*g[c0+e] + be[c0+e]);
        *reinterpret_cast<short4v*>(XN + ((size_t)(b*NN + n))*DIM + c0) = *(short4v*)pk;
    }
}

// ---------------- MFMA GEMM (K=384): MODE 0 = qkv, 1 = proj ----------------
// dbuf A via global_load_lds (swizzled), B fragments direct global->reg (L2-resident),
// 1 barrier per k-step, XCD-swizzled grid, LDS-staged coalesced epilogues.
template<int MODE>
__global__ __launch_bounds__(256) void k_gemm(
    const unsigned short* __restrict__ A, const unsigned short* __restrict__ Wt,
    const float* __restrict__ bias,
    unsigned short* __restrict__ Qb, unsigned short* __restrict__ Kb, unsigned short* __restrict__ Vt,
    const float* __restrict__ XTp, const float* __restrict__ gxca, unsigned short* __restrict__ X2p)
{
    __shared__ __align__(16) char smem[35328];
    auto ctA = (float(*)[69])smem;                     // [128][69] 35328  ([o][m])
    auto ctB = (float(*)[130])smem;                    // [64][130] 33280  ([m][o])

    constexpr int NCT = (MODE == 0) ? 9 : 3;
    constexpr int CPX = (MODE == 0) ? 441 : 147;       // 392*NCT/8
    int bid = blockIdx.x;
    int orig = (bid & 7)*CPX + (bid >> 3);
    int ct = orig % NCT, mt = orig / NCT;
    int m0 = mt*128, o0 = ct*128;
    int t = threadIdx.x;
    int wave = t >> 6, lane = t & 63;
    int wr = wave >> 1, wc = wave & 1;
    int lr = lane & 15, lg = lane >> 4;

    // A staging: source col pre-swizzled (both-sides rule for global_load_lds)
    int r0 = t >> 2;
    int swcol = (((t & 3) ^ ((t >> 3) & 3)) << 3);
    const unsigned short* a0 = A + (size_t)(m0 + r0)*384 + swcol;
    const unsigned short* a1 = A + (size_t)(m0 + 64 + r0)*384 + swcol;
    // B fragment pointers: each lane's own rows
    const unsigned short* bptr[4];
    #pragma unroll
    for (int j=0;j<4;j++) bptr[j] = Wt + (size_t)(o0 + wc*64 + j*16 + lr)*384 + lg*8;
    // LDS read col swizzle (shorts)
    int rsw = ((lr >> 1) & 3) << 3;

    auto stageA = [&](char* base, int c) {
        glds16(a0 + c, base + wave*1024);
        glds16(a1 + c, base + 4096 + wave*1024);
    };

    f32x4 acc[4][4];
    #pragma unroll
    for (int i=0;i<4;i++) for (int j=0;j<4;j++) acc[i][j] = (f32x4){0.f,0.f,0.f,0.f};

    stageA(smem, 0);
    __syncthreads();
    int cur = 0;
    for (int kk = 0; kk < 12; kk++) {
        int c = kk*32;
        if (kk < 11) stageA(smem + (cur^1)*8192, c + 32);
        short8 bfv[4];
        #pragma unroll
        for (int j=0;j<4;j++) bfv[j] = *(const short8*)(bptr[j] + c);
        auto As = (unsigned short(*)[32])(smem + cur*8192);
        short8 af[4];
        #pragma unroll
        for (int i=0;i<4;i++) af[i] = *(short8*)&As[wr*64 + i*16 + lr][lg*8 ^ rsw];
        #pragma unroll
        for (int i=0;i<4;i++)
            #pragma unroll
            for (int j=0;j<4;j++)
                acc[i][j] = __builtin_amdgcn_mfma_f32_16x16x32_bf16(af[i], bfv[j], acc[i][j], 0, 0, 0);
        __syncthreads();
        cur ^= 1;
    }

    // ---- epilogue ----
    int comp = (MODE == 0) ? (o0 / DIM) : 0;
    for (int mh = 0; mh < 2; mh++) {
        __syncthreads();
        bool useB = (MODE == 1) || (MODE == 0 && comp == 2);
        if (wr == mh) {
            if (useB) {
                #pragma unroll
                for (int i=0;i<4;i++) for (int j=0;j<4;j++) for (int r=0;r<4;r++)
                    ctB[i*16 + lg*4 + r][wc*64 + j*16 + lr] = acc[i][j][r];
            } else {
                #pragma unroll
                for (int i=0;i<4;i++) for (int j=0;j<4;j++) for (int r=0;r<4;r++)
                    ctA[wc*64 + j*16 + lr][i*16 + lg*4 + r] = acc[i][j][r];
            }
        }
        __syncthreads();
        if (MODE == 1) {
            for (int q = t; q < 1024; q += 256) {   // 64 m-rows x 16 o-segs(8)
                int row = q >> 4, seg = q & 15;
                int m = m0 + mh*64 + row; int b = m/NN; int n = m - b*NN;
                int py = n/56, px = n - py*56;
                int og0 = o0 + seg*8;
                float xv[8];
                *(float4*)xv     = *(const float4*)(XTp + (size_t)m*DIM + og0);
                *(float4*)(xv+4) = *(const float4*)(XTp + (size_t)m*DIM + og0 + 4);
                unsigned short pk[8];
                #pragma unroll
                for (int e=0;e<8;e++) {
                    float val = ctB[row][seg*8+e] + bias[og0+e];
                    pk[e] = f2bf(xv[e] + gxca[og0+e]*val);
                }
                *(short8*)(X2p + ((size_t)(b*NP + (py+1)*HP + px + 1))*DIM + og0) = *(short8*)pk;
            }
        } else if (comp < 2) {                      // Q / K: (bh,dd,N) layout
            unsigned short* Dst = (comp == 0) ? Qb : Kb;
            for (int q = t; q < 2048; q += 256) {   // 128 o-rows x 16 m-segs(4)
                int row = q >> 4, seg = q & 15;
                int og = o0 + row; int rem = og - comp*DIM;
                int hh = rem >> 6, dd = rem & 63;
                int m4 = m0 + mh*64 + seg*4; int b = m4/NN; int n = m4 - b*NN;
                float bv = bias[og];
                unsigned short pk[4];
                #pragma unroll
                for (int e=0;e<4;e++) pk[e] = f2bf(ctA[row][seg*4+e] + bv);
                *(short4v*)(Dst + ((size_t)((b*HEADS + hh)*64 + dd))*NN + n) = *(short4v*)pk;
            }
        } else {                                    // V: (bh,N,dd) layout
            for (int q = t; q < 1024; q += 256) {   // 64 m-rows x 16 o-segs(8)
                int row = q >> 4, seg = q & 15;
                int m = m0 + mh*64 + row; int b = m/NN; int n = m - b*NN;
                int og0 = o0 + seg*8; int rem0 = og0 - 2*DIM;
                int hh = rem0 >> 6, dd0 = rem0 & 63;
                unsigned short pk[8];
                #pragma unroll
                for (int e=0;e<8;e++) pk[e] = f2bf(ctB[row][seg*8+e] + bias[og0+e]);
                *(short8*)(Vt + ((size_t)((b*HEADS + hh)*NN + n))*64 + dd0) = *(short8*)pk;
            }
        }
    }
}

// ---------------- conv3x3 + BN + SiLU + residual ----------------
// dbuf A-halo (swizzled glds), B fragments global->reg, barrier-free 9-tap inner loop.
__global__ __launch_bounds__(256) void k_conv(
    const unsigned short* __restrict__ A, const unsigned short* __restrict__ Wt,
    const float* __restrict__ bn_g, const float* __restrict__ bn_b,
    const float* __restrict__ bn_mean, const float* __restrict__ bn_var,
    float* __restrict__ Yout)
{
    __shared__ __align__(16) char smem[32768];
    auto ctA = (float(*)[69])smem;                     // [64][69] 17664
    auto X2s = (unsigned short(*)[72])(smem + 17664);  // [64][72] 9216

    int bid = blockIdx.x;                 // 1200 = 8*150
    int orig = (bid & 7)*150 + (bid >> 3);
    int ct = orig % 3; int rest = orig / 3;
    int tile = rest % 25; int b = rest / 25;
    int n0 = tile*128, o0 = ct*128;
    int t = threadIdx.x;
    int wave = t >> 6, lane = t & 63;
    int wr = wave >> 1, wc = wave & 1;
    int lr = lane & 15, lg = lane >> 4;
    int qb = n0 + 2*(n0/56);
    const size_t bbase = (size_t)b*NP*DIM;

    // A-halo staging sources (pre-swizzled col), 1024 tasks = 4/thread
    int swcol = (((t & 3) ^ ((t >> 3) & 3)) << 3);
    const unsigned short* asrc[4];
    #pragma unroll
    for (int j=0;j<4;j++) {
        int task = j*256 + t;
        int row = task >> 2;
        int q = qb + row; if (q > NP-1) q = NP-1;
        asrc[j] = A + bbase + (size_t)q*DIM + swcol;
    }
    // B fragment pointers: lane's own 4 rows
    const unsigned short* bptr[4];
    #pragma unroll
    for (int j=0;j<4;j++) bptr[j] = Wt + (size_t)(o0 + wc*64 + j*16 + lr)*3456 + lg*8;

    // per-lane MFMA A row offsets (position-relative)
    int qrel[4];
    #pragma unroll
    for (int i=0;i<4;i++) {
        int loc = wr*64 + i*16 + lr;
        int n = n0 + loc; if (n >= NN) n = NN-1;
        qrel[i] = n + 2*(n/56) - qb;
    }

    auto stageA = [&](char* base, int c) {
        #pragma unroll
        for (int j=0;j<4;j++) glds16(asrc[j] + c, base + j*4096 + wave*1024);
    };

    f32x4 acc[4][4];
    #pragma unroll
    for (int i=0;i<4;i++) for (int j=0;j<4;j++) acc[i][j] = (f32x4){0.f,0.f,0.f,0.f};

    stageA(smem, 0);
    __syncthreads();
    int cur = 0;
    for (int kk = 0; kk < 12; kk++) {
        int c = kk*32;
        if (kk < 11) stageA(smem + (cur^1)*16384, c + 32);
        auto Ah = (unsigned short(*)[32])(smem + cur*16384);
        #pragma unroll
        for (int tap = 0; tap < 9; tap++) {
            int toff = (tap/3)*58 + (tap%3);
            short8 bfv[4];
            #pragma unroll
            for (int j=0;j<4;j++) bfv[j] = *(const short8*)(bptr[j] + tap*384 + c);
            short8 af[4];
            #pragma unroll
            for (int i=0;i<4;i++) {
                int row = qrel[i] + toff;
                af[i] = *(short8*)&Ah[row][(lg*8) ^ (((row>>1)&3)<<3)];
            }
            #pragma unroll
            for (int i=0;i<4;i++)
                #pragma unroll
                for (int j=0;j<4;j++)
                    acc[i][j] = __builtin_amdgcn_mfma_f32_16x16x32_bf16(af[i], bfv[j], acc[i][j], 0, 0, 0);
        }
        __syncthreads();
        cur ^= 1;
    }

    // ---- epilogue: 4 quadrant passes (mh x oh), coalesced float4 writes ----
    for (int mh = 0; mh < 2; mh++) {
        for (int oh = 0; oh < 2; oh++) {
            __syncthreads();
            if (wr == mh && wc == oh) {
                #pragma unroll
                for (int i=0;i<4;i++) for (int j=0;j<4;j++) for (int r=0;r<4;r++)
                    ctA[j*16 + lr][i*16 + lg*4 + r] = acc[i][j][r];
            }
            for (int q = t; q < 512; q += 256) {    // residual: 64 m-rows x 8 o-segs(8)
                int row = q >> 3, sg = q & 7;
                int n = n0 + mh*64 + row; int nc = (n < NN) ? n : NN-1;
                int qq = nc + 2*(nc/56) + 59;       // center tap (+1,+1)
                *(short8*)&X2s[row][sg*8] =
                    *(const short8*)(A + bbase + (size_t)qq*DIM + o0 + oh*64 + sg*8);
            }
            __syncthreads();
            for (int q = t; q < 1024; q += 256) {   // 64 o-rows x 16 m-segs(4)
                int orow = q >> 4, sg = q & 15;
                int o = o0 + oh*64 + orow;
                int n = n0 + mh*64 + sg*4;
                if (n < NN) {
                    float mean = bn_mean[o], rs = rsqrtf(bn_var[o] + 1e-5f);
                    float gg = bn_g[o], bb2 = bn_b[o];
                    float4 ov; float* po = &ov.x;
                    #pragma unroll
                    for (int e=0;e<4;e++) {
                        float xi = (ctA[orow][sg*4+e] - mean)*rs*gg + bb2;
                        float si = xi / (1.0f + __expf(-xi));
                        po[e] = si + bf2f(X2s[sg*4+e][orow]);
                    }
                    *(float4*)(Yout + ((size_t)(b*DIM + o))*NN + n) = ov;
                }
            }
        }
    }
}

// ---------------- XCA attention: norms + G=q k^T + softmax -> ATT bf16 ----------------
__global__ __launch_bounds__(256) void k_attn(const unsigned short* __restrict__ Qb,
                                              const unsigned short* __restrict__ Kb,
                                              const float* __restrict__ temperature,
                                              const float* __restrict__ rpb,
                                              unsigned short* __restrict__ ATT) {
    int bh = blockIdx.x; int h = bh % HEADS;
    int t = threadIdx.x, wave = t >> 6, lane = t & 63;
    int lr = lane & 15, lg = lane >> 4;
    __shared__ float qn[64], kn[64];
    // squared norms: wave-cooperative, fully coalesced (1 KB per row-iteration)
    for (int rr = wave; rr < 128; rr += 4) {
        const unsigned short* src = (rr < 64) ? Qb + ((size_t)bh*64 + rr)*NN
                                              : Kb + ((size_t)bh*64 + (rr-64))*NN;
        float s = 0.f;
        #pragma unroll
        for (int it = 0; it < 6; it++) {
            short8 v = *reinterpret_cast<const short8*>(src + it*512 + lane*8);
            #pragma unroll
            for (int jj=0;jj<8;jj++) { float f = bf2f((unsigned short)v[jj]); s += f*f; }
        }
        { float f = bf2f(src[3072 + lane]); s += f*f; }   // tail 64
        for (int off = 32; off; off >>= 1) s += __shfl_xor(s, off, 64);
        if (lane == 0) { if (rr < 64) qn[rr] = s; else kn[rr-64] = s; }
    }
    __syncthreads();
    f32x4 acc[4];
    for (int j=0;j<4;j++) acc[j] = (f32x4){0.f,0.f,0.f,0.f};
    const unsigned short* qrow = Qb + ((size_t)bh*64 + wave*16 + lr)*NN;
    for (int ks = 0; ks < NN/32; ks++) {
        short8 a = *reinterpret_cast<const short8*>(qrow + ks*32 + lg*8);
        for (int j=0;j<4;j++) {
            short8 bfr = *reinterpret_cast<const short8*>(Kb + ((size_t)bh*64 + j*16 + lr)*NN + ks*32 + lg*8);
            acc[j] = __builtin_amdgcn_mfma_f32_16x16x32_bf16(a, bfr, acc[j], 0, 0, 0);
        }
    }
    float temp = temperature[h];
    float bias = rpb[HEADS + h];   // rpb_table[1][h]
    for (int r=0;r<4;r++) {
        int dq = wave*16 + lg*4 + r;
        float qnorm = fmaxf(sqrtf(qn[dq]), 1e-12f);
        float lv[4]; float mx = -1e30f;
        for (int j=0;j<4;j++) {
            float knorm = fmaxf(sqrtf(kn[j*16 + lr]), 1e-12f);
            lv[j] = acc[j][r] / (qnorm*knorm) * temp + bias;
            mx = fmaxf(mx, lv[j]);
        }
        for (int off=1; off<16; off<<=1) mx = fmaxf(mx, __shfl_xor(mx, off, 64));
        float se = 0.f;
        for (int j=0;j<4;j++) { lv[j] = __expf(lv[j]-mx); se += lv[j]; }
        for (int off=1; off<16; off<<=1) se += __shfl_xor(se, off, 64);
        float inv = 1.0f/se;
        for (int j=0;j<4;j++)
            ATT[((size_t)bh*64 + dq)*64 + j*16 + lr] = f2bf(lv[j]*inv);
    }
}

// ---------------- PV: XCA[b][n][h*64+dd] = sum_e ATT[dd][e] * V[e][n] ----------------
__global__ __launch_bounds__(256) void k_pv(const unsigned short* __restrict__ ATT,
                                            const unsigned short* __restrict__ Vt,
                                            unsigned short* __restrict__ XCA) {
    int nt = blockIdx.x, bh = blockIdx.y;
    int b = bh / HEADS, h = bh % HEADS;
    int t = threadIdx.x, wave = t >> 6, lane = t & 63;
    int lr = lane & 15, lg = lane >> 4;
    int n0 = nt*64;
    __shared__ float ctP[64][67];
    f32x4 acc[4];
    for (int i=0;i<4;i++) acc[i] = (f32x4){0.f,0.f,0.f,0.f};
    for (int ks=0; ks<2; ks++) {
        short8 bfr = *reinterpret_cast<const short8*>(Vt + ((size_t)bh*NN + n0 + wave*16 + lr)*64 + ks*32 + lg*8);
        for (int i=0;i<4;i++) {
            short8 a = *reinterpret_cast<const short8*>(ATT + ((size_t)bh*64 + i*16 + lr)*64 + ks*32 + lg*8);
            acc[i] = __builtin_amdgcn_mfma_f32_16x16x32_bf16(a, bfr, acc[i], 0, 0, 0);
        }
    }
    int nl = wave*16 + lr;
    #pragma unroll
    for (int i=0;i<4;i++)
        #pragma unroll
        for (int r=0;r<4;r++) ctP[nl][i*16 + lg*4 + r] = acc[i][r];
    __syncthreads();
    for (int q = t; q < 512; q += 256) {   // 64 n-rows x 8 dd-segs(8)
        int row = q >> 3, seg = q & 7;
        unsigned short pk[8];
        #pragma unroll
        for (int e=0;e<8;e++) pk[e] = f2bf(ctP[row][seg*8+e]);
        *(short8*)(XCA + ((size_t)(b*NN + n0 + row))*DIM + h*64 + seg*8) = *(short8*)pk;
    }
}

// ---------------- final: out = x + gamma-shuffled residual ----------------
__global__ __launch_bounds__(256) void k_final(const float* __restrict__ x, const float* __restrict__ Y,
                                               const float* __restrict__ gamma, float* __restrict__ out) {
    int i = blockIdx.x, b = blockIdx.y, kc = blockIdx.z;
    __shared__ float tile[56*193];
    int t = threadIdx.x;
    int k0 = kc*192;
    const float* ybase = Y + (size_t)b*DIM*NN + (size_t)i*21504 + k0;
    for (int q = t; q < 56*48; q += 256) {
        int j = q / 48, c4 = (q % 48) * 4;
        float4 v = *reinterpret_cast<const float4*>(ybase + (size_t)j*384 + c4);
        float* dst = &tile[j*193 + c4];
        dst[0]=v.x; dst[1]=v.y; dst[2]=v.z; dst[3]=v.w;
    }
    __syncthreads();
    for (int q = t; q < 192*56; q += 256) {
        int kl = q / 56, j = q % 56;
        int k = k0 + kl;
        size_t gi = ((size_t)(b*DIM + k))*NN + (size_t)i*56 + j;
        out[gi] = x[gi] + gamma[k] * tile[j*193 + kl];
    }
}

extern "C" void kernel_launch(void* const* d_in, const int* in_sizes, int n_in,
                              void* d_out, int out_size, void* d_ws, size_t ws_size,
                              hipStream_t stream) {
    const float* x       = (const float*)d_in[0];
    const float* pos_w   = (const float*)d_in[1];
    const float* pos_b   = (const float*)d_in[2];
    const float* ln_g    = (const float*)d_in[3];
    const float* ln_b    = (const float*)d_in[4];
    const float* gxca    = (const float*)d_in[5];
    const float* temp    = (const float*)d_in[6];
    const float* qkv_w   = (const float*)d_in[7];
    const float* qkv_b   = (const float*)d_in[8];
    const float* proj_w  = (const float*)d_in[9];
    const float* proj_b  = (const float*)d_in[10];
    const float* rpb     = (const float*)d_in[11];
    const float* conv_w  = (const float*)d_in[12];
    const float* bn_g    = (const float*)d_in[13];
    const float* bn_b    = (const float*)d_in[14];
    const float* bn_mean = (const float*)d_in[15];
    const float* bn_var  = (const float*)d_in[16];
    const float* gamma   = (const float*)d_in[17];
    float* out = (float*)d_out;
    char* ws = (char*)d_ws;

    const size_t oP   = 0;                        // P: 4,816,896 B
    const size_t oXT  = oP   + 4816896;           // XT fp32: 77,070,336 B   (reused as Y)
    const size_t oXN  = oXT  + 77070336;          // XN bf16: 38,535,168 B   (reused as XCA)
    const size_t oQ   = oXN  + 38535168;          // Qb bf16                  (reused as X2p padded, spans into Kb)
    const size_t oK   = oQ   + 38535168;          // Kb bf16
    const size_t oV   = oK   + 38535168;          // Vt bf16
    const size_t oATT = oV   + 38535168;          // ATT bf16: 786,432 B
    const size_t oWq  = oATT + 786432;            // 884,736 B
    const size_t oWp  = oWq  + 884736;            // 294,912 B
    const size_t oWc  = oWp  + 294912;            // 2,654,208 B

    float* P            = (float*)(ws + oP);
    float* XT           = (float*)(ws + oXT);
    float* Y            = (float*)(ws + oXT);     // alias (XT dead after proj epilogue)
    unsigned short* XN  = (unsigned short*)(ws + oXN);
    unsigned short* XCA = (unsigned short*)(ws + oXN);  // alias (XN dead after qkv GEMM)
    unsigned short* Qb  = (unsigned short*)(ws + oQ);
    unsigned short* X2p = (unsigned short*)(ws + oQ);   // alias (Qb+Kb dead after k_attn); 41,336,832 B padded
    unsigned short* Kb  = (unsigned short*)(ws + oK);
    unsigned short* Vt  = (unsigned short*)(ws + oV);
    unsigned short* ATT = (unsigned short*)(ws + oATT);
    unsigned short* Wq  = (unsigned short*)(ws + oWq);
    unsigned short* Wp  = (unsigned short*)(ws + oWp);
    unsigned short* Wc  = (unsigned short*)(ws + oWc);

    kw_convert<<<256, 256, 0, stream>>>(qkv_w, proj_w, conv_w, Wq, Wp, Wc);
    k_pos<<<NN, 128, 0, stream>>>(pos_w, pos_b, P);
    k_tln<<<BB*98, 256, 0, stream>>>(x, P, ln_g, ln_b, XT, XN);
    k_gemm<0><<<3528, 256, 0, stream>>>(XN, Wq, qkv_b,
        Qb, Kb, Vt, nullptr, nullptr, nullptr);
    k_attn<<<BH, 256, 0, stream>>>(Qb, Kb, temp, rpb, ATT);
    // Q/K dead now; zero the padded X2 buffer (pad ring must be 0)
    hipMemsetAsync(X2p, 0, (size_t)BB*NP*DIM*2, stream);
    k_pv<<<dim3(49, BH), 256, 0, stream>>>(ATT, Vt, XCA);
    k_gemm<1><<<1176, 256, 0, stream>>>(XCA, Wp, proj_b,
        nullptr, nullptr, nullptr, XT, gxca, X2p);
    k_conv<<<1200, 256, 0, stream>>>(X2p, Wc, bn_g, bn_b, bn_mean, bn_var, Y);
    k_final<<<dim3(56, BB, 2), 256, 0, stream>>>(x, Y, gamma, out);
}

// Round 5
// 531.459 us; speedup vs baseline: 1.4540x; 1.4540x over previous
//
#include <hip/hip_runtime.h>
#include <hip/hip_bf16.h>
#include <math.h>

#define DIM 384
#define HEADS 6
#define NN 3136
#define BB 16
#define BH (BB*HEADS)
#define HP 58
#define NP (HP*HP)   // 3364 padded image

typedef __attribute__((ext_vector_type(8))) short short8;
typedef __attribute__((ext_vector_type(4))) short short4v;
typedef __attribute__((ext_vector_type(4))) float f32x4;

__device__ __forceinline__ float bf2f(unsigned short u) {
    union { unsigned int i; float f; } v; v.i = ((unsigned int)u) << 16; return v.f;
}
__device__ __forceinline__ unsigned short f2bf(float f) {
    union { float f; unsigned int i; } v; v.f = f;
    unsigned int r = v.i + 0x7fffu + ((v.i >> 16) & 1u);
    return (unsigned short)(r >> 16);
}
__device__ __forceinline__ void glds16(const unsigned short* g, void* l) {
    __builtin_amdgcn_global_load_lds(
        (const __attribute__((address_space(1))) unsigned int*)g,
        (__attribute__((address_space(3))) unsigned int*)l, 16, 0, 0);
}

// ---------------- weight conversion / rearrange ----------------
__global__ void kw_convert(const float* __restrict__ qkv_w, const float* __restrict__ proj_w,
                           const float* __restrict__ conv_w,
                           unsigned short* __restrict__ Wq, unsigned short* __restrict__ Wp,
                           unsigned short* __restrict__ Wc) {
    int tid = blockIdx.x * 256 + threadIdx.x;
    int stride = gridDim.x * 256;
    for (int i = tid; i < 3*DIM*DIM; i += stride) Wq[i] = f2bf(qkv_w[i]);
    for (int i = tid; i < DIM*DIM; i += stride) Wp[i] = f2bf(proj_w[i]);
    for (int i = tid; i < DIM*DIM*9; i += stride) {
        // dst layout: [o][tap][i]   src: (o, i, ky, kx) -> (o*384+i)*9 + tap
        int ii = i % DIM; int rest = i / DIM; int tap = rest % 9; int o = rest / 9;
        Wc[i] = f2bf(conv_w[(size_t)(o*DIM + ii)*9 + tap]);
    }
}

// ---------------- positional encoding table P[n][c] ----------------
__global__ void k_pos(const float* __restrict__ pos_w, const float* __restrict__ pos_b,
                      float* __restrict__ P) {
    int n = blockIdx.x; int h = n / 56, w = n % 56;
    __shared__ float feat[64];
    int t = threadIdx.x;
    if (t < 64) {
        int axis = t >> 5;      // 0 = y (h), 1 = x (w)
        int k = t & 31; int i = k >> 1;
        float e = (float)((axis ? w : h) + 1) / 56.000001f * 6.28318530717958647692f;
        float arg = e / powf(10000.0f, (float)i / 16.0f);
        feat[t] = (k & 1) ? cosf(arg) : sinf(arg);
    }
    __syncthreads();
    for (int c = t; c < DIM; c += blockDim.x) {
        float s = pos_b[c];
        #pragma unroll 8
        for (int k = 0; k < 64; k++) s += feat[k] * pos_w[c*64 + k];
        P[(size_t)n*DIM + c] = s;
    }
}

// ---------------- fused transpose + pos add + layernorm ----------------
__global__ __launch_bounds__(256) void k_tln(const float* __restrict__ x, const float* __restrict__ P,
                                             const float* __restrict__ g, const float* __restrict__ be,
                                             float* __restrict__ XT, unsigned short* __restrict__ XN) {
    __shared__ float tile[32][388];
    int blk = blockIdx.x;
    int b = blk / 98, nt = blk % 98;
    int n0 = nt*32;
    int t = threadIdx.x;
    #pragma unroll
    for (int it = 0; it < 12; it++) {
        int task = it*256 + t;
        int c = task >> 3, seg = task & 7;
        float4 v = *reinterpret_cast<const float4*>(x + ((size_t)(b*DIM + c))*NN + n0 + seg*4);
        tile[seg*4+0][c] = v.x; tile[seg*4+1][c] = v.y;
        tile[seg*4+2][c] = v.z; tile[seg*4+3][c] = v.w;
    }
    __syncthreads();
    int row = t >> 3, sub = t & 7;
    int n = n0 + row;
    f32x4 xp[12];
    float s = 0.f;
    #pragma unroll
    for (int k = 0; k < 12; k++) {
        int c0 = (k*8 + sub)*4;
        float4 tv = *reinterpret_cast<float4*>(&tile[row][c0]);
        float4 pv = *reinterpret_cast<const float4*>(P + (size_t)n*DIM + c0);
        f32x4 xv = {tv.x+pv.x, tv.y+pv.y, tv.z+pv.z, tv.w+pv.w};
        xp[k] = xv;
        s += xv[0]+xv[1]+xv[2]+xv[3];
        *reinterpret_cast<float4*>(XT + ((size_t)(b*NN + n))*DIM + c0) = *(float4*)&xv;
    }
    s += __shfl_xor(s, 1, 64); s += __shfl_xor(s, 2, 64); s += __shfl_xor(s, 4, 64);
    float mean = s * (1.0f/384.0f);
    float sq = 0.f;
    #pragma unroll
    for (int k = 0; k < 12; k++) {
        #pragma unroll
        for (int e = 0; e < 4; e++) { float d = xp[k][e]-mean; sq += d*d; }
    }
    sq += __shfl_xor(sq, 1, 64); sq += __shfl_xor(sq, 2, 64); sq += __shfl_xor(sq, 4, 64);
    float rs = rsqrtf(sq * (1.0f/384.0f) + 1e-6f);
    #pragma unroll
    for (int k = 0; k < 12; k++) {
        int c0 = (k*8 + sub)*4;
        unsigned short pk[4];
        #pragma unroll
        for (int e = 0; e < 4; e++)
            pk[e] = f2bf((xp[k][e]-mean)*rs*g[c0+e] + be[c0+e]);
        *reinterpret_cast<short4v*>(XN + ((size_t)(b*NN + n))*DIM + c0) = *(short4v*)pk;
    }
}

// ---------------- MFMA GEMM (K=384): MODE 0 = qkv, 1 = proj ----------------
// A+B double-buffered via swizzled global_load_lds, 1 barrier per k-step.
template<int MODE>
__global__ __launch_bounds__(256) void k_gemm(
    const unsigned short* __restrict__ A, const unsigned short* __restrict__ Wt,
    const float* __restrict__ bias,
    unsigned short* __restrict__ Qb, unsigned short* __restrict__ Kb, unsigned short* __restrict__ Vt,
    const float* __restrict__ XTp, const float* __restrict__ gxca, unsigned short* __restrict__ X2p)
{
    __shared__ __align__(16) char smem[35328];
    auto ctA = (float(*)[69])smem;                     // [128][69] 35328  ([o][m])
    auto ctB = (float(*)[130])smem;                    // [64][130] 33280  ([m][o])

    constexpr int NCT = (MODE == 0) ? 9 : 3;
    constexpr int CPX = (MODE == 0) ? 441 : 147;       // 392*NCT/8
    int bid = blockIdx.x;
    int orig = (bid & 7)*CPX + (bid >> 3);
    int ct = orig % NCT, mt = orig / NCT;
    int m0 = mt*128, o0 = ct*128;
    int t = threadIdx.x;
    int wave = t >> 6, lane = t & 63;
    int wr = wave >> 1, wc = wave & 1;
    int lr = lane & 15, lg = lane >> 4;

    // staging: source col pre-swizzled (both-sides rule for global_load_lds)
    int r0 = t >> 2;
    int swcol = (((t & 3) ^ ((t >> 3) & 3)) << 3);
    const unsigned short* a0 = A  + (size_t)(m0 + r0)*384 + swcol;
    const unsigned short* a1 = A  + (size_t)(m0 + 64 + r0)*384 + swcol;
    const unsigned short* b0 = Wt + (size_t)(o0 + r0)*384 + swcol;
    const unsigned short* b1 = Wt + (size_t)(o0 + 64 + r0)*384 + swcol;
    int rsw = ((lr >> 1) & 3) << 3;    // read-side swizzle (shorts)

    auto stage = [&](char* base, int c) {
        glds16(a0 + c, base + wave*1024);
        glds16(a1 + c, base + 4096 + wave*1024);
        glds16(b0 + c, base + 8192 + wave*1024);
        glds16(b1 + c, base + 12288 + wave*1024);
    };

    f32x4 acc[4][4];
    #pragma unroll
    for (int i=0;i<4;i++) for (int j=0;j<4;j++) acc[i][j] = (f32x4){0.f,0.f,0.f,0.f};

    stage(smem, 0);
    __syncthreads();
    for (int kk = 0; kk < 12; kk++) {
        if (kk < 11) stage(smem + ((kk+1)&1)*16384, (kk+1)*32);
        auto As = (unsigned short(*)[32])(smem + (kk&1)*16384);
        auto Bs = (unsigned short(*)[32])(smem + (kk&1)*16384 + 8192);
        short8 af[4], bfv[4];
        #pragma unroll
        for (int i=0;i<4;i++) af[i]  = *(short8*)&As[wr*64 + i*16 + lr][(lg*8) ^ rsw];
        #pragma unroll
        for (int j=0;j<4;j++) bfv[j] = *(short8*)&Bs[wc*64 + j*16 + lr][(lg*8) ^ rsw];
        #pragma unroll
        for (int i=0;i<4;i++)
            #pragma unroll
            for (int j=0;j<4;j++)
                acc[i][j] = __builtin_amdgcn_mfma_f32_16x16x32_bf16(af[i], bfv[j], acc[i][j], 0, 0, 0);
        __syncthreads();
    }

    // ---- epilogue ----
    int comp = (MODE == 0) ? (o0 / DIM) : 0;
    for (int mh = 0; mh < 2; mh++) {
        __syncthreads();
        bool useB = (MODE == 1) || (MODE == 0 && comp == 2);
        if (wr == mh) {
            if (useB) {
                #pragma unroll
                for (int i=0;i<4;i++) for (int j=0;j<4;j++) for (int r=0;r<4;r++)
                    ctB[i*16 + lg*4 + r][wc*64 + j*16 + lr] = acc[i][j][r];
            } else {
                #pragma unroll
                for (int i=0;i<4;i++) for (int j=0;j<4;j++) for (int r=0;r<4;r++)
                    ctA[wc*64 + j*16 + lr][i*16 + lg*4 + r] = acc[i][j][r];
            }
        }
        __syncthreads();
        if (MODE == 1) {
            for (int q = t; q < 1024; q += 256) {   // 64 m-rows x 16 o-segs(8)
                int row = q >> 4, seg = q & 15;
                int m = m0 + mh*64 + row; int b = m/NN; int n = m - b*NN;
                int py = n/56, px = n - py*56;
                int og0 = o0 + seg*8;
                float xv[8];
                *(float4*)xv     = *(const float4*)(XTp + (size_t)m*DIM + og0);
                *(float4*)(xv+4) = *(const float4*)(XTp + (size_t)m*DIM + og0 + 4);
                unsigned short pk[8];
                #pragma unroll
                for (int e=0;e<8;e++) {
                    float val = ctB[row][seg*8+e] + bias[og0+e];
                    pk[e] = f2bf(xv[e] + gxca[og0+e]*val);
                }
                *(short8*)(X2p + ((size_t)(b*NP + (py+1)*HP + px + 1))*DIM + og0) = *(short8*)pk;
            }
        } else if (comp < 2) {                      // Q / K: (bh,dd,N) layout
            unsigned short* Dst = (comp == 0) ? Qb : Kb;
            for (int q = t; q < 2048; q += 256) {   // 128 o-rows x 16 m-segs(4)
                int row = q >> 4, seg = q & 15;
                int og = o0 + row; int rem = og - comp*DIM;
                int hh = rem >> 6, dd = rem & 63;
                int m4 = m0 + mh*64 + seg*4; int b = m4/NN; int n = m4 - b*NN;
                float bv = bias[og];
                unsigned short pk[4];
                #pragma unroll
                for (int e=0;e<4;e++) pk[e] = f2bf(ctA[row][seg*4+e] + bv);
                *(short4v*)(Dst + ((size_t)((b*HEADS + hh)*64 + dd))*NN + n) = *(short4v*)pk;
            }
        } else {                                    // V: (bh,N,dd) layout
            for (int q = t; q < 1024; q += 256) {   // 64 m-rows x 16 o-segs(8)
                int row = q >> 4, seg = q & 15;
                int m = m0 + mh*64 + row; int b = m/NN; int n = m - b*NN;
                int og0 = o0 + seg*8; int rem0 = og0 - 2*DIM;
                int hh = rem0 >> 6, dd0 = rem0 & 63;
                unsigned short pk[8];
                #pragma unroll
                for (int e=0;e<8;e++) pk[e] = f2bf(ctB[row][seg*8+e] + bias[og0+e]);
                *(short8*)(Vt + ((size_t)((b*HEADS + hh)*NN + n))*64 + dd0) = *(short8*)pk;
            }
        }
    }
}

// ---------------- conv3x3 + BN + SiLU + residual ----------------
// A-halo single-buffer + B tap-double-buffer, both swizzled glds staging.
__global__ __launch_bounds__(256) void k_conv(
    const unsigned short* __restrict__ A, const unsigned short* __restrict__ Wt,
    const float* __restrict__ bn_g, const float* __restrict__ bn_b,
    const float* __restrict__ bn_mean, const float* __restrict__ bn_var,
    float* __restrict__ Yout)
{
    __shared__ __align__(16) char smem[32768];
    // k-loop: A halo [256][32] @0 (16384), B dbuf 2x[128][32] @16384
    auto ctA = (float(*)[69])smem;                     // [64][69] 17664
    auto X2s = (unsigned short(*)[68])(smem + 17664);  // [64][68] 8704

    int bid = blockIdx.x;                 // 1200 = 8*150
    int orig = (bid & 7)*150 + (bid >> 3);
    int ct = orig % 3; int rest = orig / 3;
    int tile = rest % 25; int b = rest / 25;
    int n0 = tile*128, o0 = ct*128;
    int t = threadIdx.x;
    int wave = t >> 6, lane = t & 63;
    int wr = wave >> 1, wc = wave & 1;
    int lr = lane & 15, lg = lane >> 4;
    int qb = n0 + 2*(n0/56);
    const size_t bbase = (size_t)b*NP*DIM;

    int swcol = (((t & 3) ^ ((t >> 3) & 3)) << 3);
    const unsigned short* asrc[4];
    #pragma unroll
    for (int j=0;j<4;j++) {
        int task = j*256 + t;
        int row = task >> 2;
        int q = qb + row; if (q > NP-1) q = NP-1;
        asrc[j] = A + bbase + (size_t)q*DIM + swcol;
    }
    const unsigned short* bsrc0 = Wt + (size_t)(o0 + (t>>2))*3456 + swcol;
    const unsigned short* bsrc1 = Wt + (size_t)(o0 + 64 + (t>>2))*3456 + swcol;

    // per-lane MFMA A row offsets (position-relative)
    int qrel[4];
    #pragma unroll
    for (int i=0;i<4;i++) {
        int loc = wr*64 + i*16 + lr;
        int n = n0 + loc; if (n >= NN) n = NN-1;
        qrel[i] = n + 2*(n/56) - qb;
    }

    auto stageA = [&](int c) {
        #pragma unroll
        for (int j=0;j<4;j++) glds16(asrc[j] + c, smem + j*4096 + wave*1024);
    };
    auto stageB = [&](char* base, int off) {
        glds16(bsrc0 + off, base + wave*1024);
        glds16(bsrc1 + off, base + 4096 + wave*1024);
    };

    f32x4 acc[4][4];
    #pragma unroll
    for (int i=0;i<4;i++) for (int j=0;j<4;j++) acc[i][j] = (f32x4){0.f,0.f,0.f,0.f};

    stageA(0); stageB(smem + 16384, 0);
    __syncthreads();
    for (int kk = 0; kk < 12; kk++) {
        int c = kk*32;
        auto Ah = (unsigned short(*)[32])smem;
        #pragma unroll
        for (int tap = 0; tap < 9; tap++) {
            int buf = tap & 1;
            if (tap < 8) stageB(smem + 16384 + (buf^1)*8192, (tap+1)*384 + c);
            auto Bs = (unsigned short(*)[32])(smem + 16384 + buf*8192);
            int toff = (tap/3)*58 + (tap%3);
            short8 af[4], bfv[4];
            #pragma unroll
            for (int j=0;j<4;j++)
                bfv[j] = *(short8*)&Bs[wc*64 + j*16 + lr][(lg*8) ^ (((lr>>1)&3)<<3)];
            #pragma unroll
            for (int i=0;i<4;i++) {
                int row = qrel[i] + toff;
                af[i] = *(short8*)&Ah[row][(lg*8) ^ (((row>>1)&3)<<3)];
            }
            #pragma unroll
            for (int i=0;i<4;i++)
                #pragma unroll
                for (int j=0;j<4;j++)
                    acc[i][j] = __builtin_amdgcn_mfma_f32_16x16x32_bf16(af[i], bfv[j], acc[i][j], 0, 0, 0);
            __syncthreads();
        }
        if (kk < 11) {
            stageA(c + 32);
            stageB(smem + 16384, c + 32);   // (kk+1, tap0) into buf0
            __syncthreads();
        }
    }

    // ---- epilogue: 4 quadrant passes (mh x oh), coalesced float4 writes ----
    for (int mh = 0; mh < 2; mh++) {
        for (int oh = 0; oh < 2; oh++) {
            __syncthreads();
            if (wr == mh && wc == oh) {
                #pragma unroll
                for (int i=0;i<4;i++) for (int j=0;j<4;j++) for (int r=0;r<4;r++)
                    ctA[j*16 + lr][i*16 + lg*4 + r] = acc[i][j][r];
            }
            for (int q = t; q < 512; q += 256) {    // residual: 64 m-rows x 8 o-segs(8)
                int row = q >> 3, sg = q & 7;
                int n = n0 + mh*64 + row; int nc = (n < NN) ? n : NN-1;
                int qq = nc + 2*(nc/56) + 59;       // center tap (+1,+1)
                short8 v = *(const short8*)(A + bbase + (size_t)qq*DIM + o0 + oh*64 + sg*8);
                short4v lo = {v[0],v[1],v[2],v[3]}, hi = {v[4],v[5],v[6],v[7]};
                *(short4v*)&X2s[row][sg*8]     = lo;
                *(short4v*)&X2s[row][sg*8 + 4] = hi;
            }
            __syncthreads();
            for (int q = t; q < 1024; q += 256) {   // 64 o-rows x 16 m-segs(4)
                int orow = q >> 4, sg = q & 15;
                int o = o0 + oh*64 + orow;
                int n = n0 + mh*64 + sg*4;
                if (n < NN) {
                    float mean = bn_mean[o], rs = rsqrtf(bn_var[o] + 1e-5f);
                    float gg = bn_g[o], bb2 = bn_b[o];
                    float4 ov; float* po = &ov.x;
                    #pragma unroll
                    for (int e=0;e<4;e++) {
                        float xi = (ctA[orow][sg*4+e] - mean)*rs*gg + bb2;
                        float si = xi / (1.0f + __expf(-xi));
                        po[e] = si + bf2f(X2s[sg*4+e][orow]);
                    }
                    *(float4*)(Yout + ((size_t)(b*DIM + o))*NN + n) = ov;
                }
            }
        }
    }
}

// ---------------- attention stage 1: partial G = q k^T + partial sq-norms ----------------
// grid (7 chunks, 96 bh); chunk = 448 columns (3136 = 7*448)
__global__ __launch_bounds__(256) void k_qk(const unsigned short* __restrict__ Qb,
                                            const unsigned short* __restrict__ Kb,
                                            float* __restrict__ Gp, float* __restrict__ Np) {
    int cx = blockIdx.x, bh = blockIdx.y;
    int t = threadIdx.x, wave = t >> 6, lane = t & 63;
    int lr = lane & 15, lg = lane >> 4;
    {   // partial squared norms: 128 rows x 2 threads
        int row = t >> 1, p = t & 1;
        const unsigned short* src = (row < 64)
            ? Qb + ((size_t)bh*64 + row)*NN + cx*448
            : Kb + ((size_t)bh*64 + (row-64))*NN + cx*448;
        float s = 0.f;
        #pragma unroll
        for (int it = 0; it < 28; it++) {
            short8 v = *(const short8*)(src + p*224 + it*8);
            #pragma unroll
            for (int jj=0;jj<8;jj++) { float f = bf2f((unsigned short)v[jj]); s += f*f; }
        }
        s += __shfl_xor(s, 1, 64);
        if (p == 0) Np[((size_t)bh*7 + cx)*128 + row] = s;
    }
    f32x4 acc[4];
    #pragma unroll
    for (int j=0;j<4;j++) acc[j] = (f32x4){0.f,0.f,0.f,0.f};
    const unsigned short* qrow = Qb + ((size_t)bh*64 + wave*16 + lr)*NN + cx*448;
    const unsigned short* kbase = Kb + (size_t)bh*64*NN + cx*448;
    for (int ks = 0; ks < 14; ks++) {
        short8 a = *(const short8*)(qrow + ks*32 + lg*8);
        #pragma unroll
        for (int j=0;j<4;j++) {
            short8 bfr = *(const short8*)(kbase + (size_t)(j*16+lr)*NN + ks*32 + lg*8);
            acc[j] = __builtin_amdgcn_mfma_f32_16x16x32_bf16(a, bfr, acc[j], 0, 0, 0);
        }
    }
    float* gbase = Gp + ((size_t)bh*7 + cx)*4096;
    #pragma unroll
    for (int j=0;j<4;j++)
        #pragma unroll
        for (int r=0;r<4;r++)
            gbase[(wave*16 + lg*4 + r)*64 + j*16 + lr] = acc[j][r];
}

// ---------------- attention stage 2: combine + normalize + softmax -> ATT ----------------
__global__ __launch_bounds__(256) void k_sm(const float* __restrict__ Gp, const float* __restrict__ Np,
                                            const float* __restrict__ temperature,
                                            const float* __restrict__ rpb,
                                            unsigned short* __restrict__ ATT) {
    int bh = blockIdx.x; int h = bh % HEADS;
    int t = threadIdx.x;
    __shared__ float snorm[128];
    if (t < 128) {
        float s = 0.f;
        #pragma unroll
        for (int cx=0;cx<7;cx++) s += Np[((size_t)bh*7 + cx)*128 + t];
        snorm[t] = fmaxf(sqrtf(s), 1e-12f);
    }
    __syncthreads();
    int dq = t >> 2, de0 = (t & 3) * 16;
    f32x4 g[4];
    #pragma unroll
    for (int i=0;i<4;i++) g[i] = (f32x4){0.f,0.f,0.f,0.f};
    #pragma unroll
    for (int cx=0;cx<7;cx++) {
        const float* base = Gp + ((size_t)bh*7 + cx)*4096 + dq*64 + de0;
        #pragma unroll
        for (int i=0;i<4;i++) {
            float4 v = *(const float4*)(base + i*4);
            g[i][0]+=v.x; g[i][1]+=v.y; g[i][2]+=v.z; g[i][3]+=v.w;
        }
    }
    float temp = temperature[h];
    float bias = rpb[HEADS + h];
    float qn = snorm[dq];
    float lv[16]; float mx = -1e30f;
    #pragma unroll
    for (int i=0;i<4;i++)
        #pragma unroll
        for (int e=0;e<4;e++) {
            int de = de0 + i*4 + e;
            float v = g[i][e] / (qn * snorm[64 + de]) * temp + bias;
            lv[i*4+e] = v; mx = fmaxf(mx, v);
        }
    mx = fmaxf(mx, __shfl_xor(mx, 1, 64));
    mx = fmaxf(mx, __shfl_xor(mx, 2, 64));
    float se = 0.f;
    #pragma unroll
    for (int e=0;e<16;e++) { lv[e] = __expf(lv[e]-mx); se += lv[e]; }
    se += __shfl_xor(se, 1, 64);
    se += __shfl_xor(se, 2, 64);
    float inv = 1.0f/se;
    unsigned short pk[16];
    #pragma unroll
    for (int e=0;e<16;e++) pk[e] = f2bf(lv[e]*inv);
    unsigned short* dst = ATT + ((size_t)bh*64 + dq)*64 + de0;
    *(short8*)dst       = *(short8*)pk;
    *(short8*)(dst + 8) = *(short8*)(pk + 8);
}

// ---------------- PV: XCA[b][n][h*64+dd] = sum_e ATT[dd][e] * V[e][n] ----------------
__global__ __launch_bounds__(256) void k_pv(const unsigned short* __restrict__ ATT,
                                            const unsigned short* __restrict__ Vt,
                                            unsigned short* __restrict__ XCA) {
    int nt = blockIdx.x, bh = blockIdx.y;
    int b = bh / HEADS, h = bh % HEADS;
    int t = threadIdx.x, wave = t >> 6, lane = t & 63;
    int lr = lane & 15, lg = lane >> 4;
    int n0 = nt*64;
    __shared__ float ctP[64][67];
    f32x4 acc[4];
    for (int i=0;i<4;i++) acc[i] = (f32x4){0.f,0.f,0.f,0.f};
    for (int ks=0; ks<2; ks++) {
        short8 bfr = *reinterpret_cast<const short8*>(Vt + ((size_t)bh*NN + n0 + wave*16 + lr)*64 + ks*32 + lg*8);
        for (int i=0;i<4;i++) {
            short8 a = *reinterpret_cast<const short8*>(ATT + ((size_t)bh*64 + i*16 + lr)*64 + ks*32 + lg*8);
            acc[i] = __builtin_amdgcn_mfma_f32_16x16x32_bf16(a, bfr, acc[i], 0, 0, 0);
        }
    }
    int nl = wave*16 + lr;
    #pragma unroll
    for (int i=0;i<4;i++)
        #pragma unroll
        for (int r=0;r<4;r++) ctP[nl][i*16 + lg*4 + r] = acc[i][r];
    __syncthreads();
    for (int q = t; q < 512; q += 256) {   // 64 n-rows x 8 dd-segs(8)
        int row = q >> 3, seg = q & 7;
        unsigned short pk[8];
        #pragma unroll
        for (int e=0;e<8;e++) pk[e] = f2bf(ctP[row][seg*8+e]);
        *(short8*)(XCA + ((size_t)(b*NN + n0 + row))*DIM + h*64 + seg*8) = *(short8*)pk;
    }
}

// ---------------- final: out = x + gamma-shuffled residual ----------------
__global__ __launch_bounds__(256) void k_final(const float* __restrict__ x, const float* __restrict__ Y,
                                               const float* __restrict__ gamma, float* __restrict__ out) {
    int i = blockIdx.x, b = blockIdx.y, kc = blockIdx.z;
    __shared__ float tile[56*193];
    int t = threadIdx.x;
    int k0 = kc*192;
    const float* ybase = Y + (size_t)b*DIM*NN + (size_t)i*21504 + k0;
    for (int q = t; q < 56*48; q += 256) {
        int j = q / 48, c4 = (q % 48) * 4;
        float4 v = *reinterpret_cast<const float4*>(ybase + (size_t)j*384 + c4);
        float* dst = &tile[j*193 + c4];
        dst[0]=v.x; dst[1]=v.y; dst[2]=v.z; dst[3]=v.w;
    }
    __syncthreads();
    for (int q = t; q < 192*56; q += 256) {
        int kl = q / 56, j = q % 56;
        int k = k0 + kl;
        size_t gi = ((size_t)(b*DIM + k))*NN + (size_t)i*56 + j;
        out[gi] = x[gi] + gamma[k] * tile[j*193 + kl];
    }
}

extern "C" void kernel_launch(void* const* d_in, const int* in_sizes, int n_in,
                              void* d_out, int out_size, void* d_ws, size_t ws_size,
                              hipStream_t stream) {
    const float* x       = (const float*)d_in[0];
    const float* pos_w   = (const float*)d_in[1];
    const float* pos_b   = (const float*)d_in[2];
    const float* ln_g    = (const float*)d_in[3];
    const float* ln_b    = (const float*)d_in[4];
    const float* gxca    = (const float*)d_in[5];
    const float* temp    = (const float*)d_in[6];
    const float* qkv_w   = (const float*)d_in[7];
    const float* qkv_b   = (const float*)d_in[8];
    const float* proj_w  = (const float*)d_in[9];
    const float* proj_b  = (const float*)d_in[10];
    const float* rpb     = (const float*)d_in[11];
    const float* conv_w  = (const float*)d_in[12];
    const float* bn_g    = (const float*)d_in[13];
    const float* bn_b    = (const float*)d_in[14];
    const float* bn_mean = (const float*)d_in[15];
    const float* bn_var  = (const float*)d_in[16];
    const float* gamma   = (const float*)d_in[17];
    float* out = (float*)d_out;
    char* ws = (char*)d_ws;

    const size_t oP   = 0;                        // P: 4,816,896 B
    const size_t oXT  = oP   + 4816896;           // XT fp32: 77,070,336 B   (reused as Y)
    const size_t oXN  = oXT  + 77070336;          // XN bf16: 38,535,168 B   (reused as Gp/Np, then XCA)
    const size_t oQ   = oXN  + 38535168;          // Qb bf16                  (reused as X2p padded, spans into Kb)
    const size_t oK   = oQ   + 38535168;          // Kb bf16
    const size_t oV   = oK   + 38535168;          // Vt bf16
    const size_t oATT = oV   + 38535168;          // ATT bf16: 786,432 B
    const size_t oWq  = oATT + 786432;            // 884,736 B
    const size_t oWp  = oWq  + 884736;            // 294,912 B
    const size_t oWc  = oWp  + 294912;            // 2,654,208 B

    float* P            = (float*)(ws + oP);
    float* XT           = (float*)(ws + oXT);
    float* Y            = (float*)(ws + oXT);     // alias (XT dead after proj epilogue)
    unsigned short* XN  = (unsigned short*)(ws + oXN);
    float* Gp           = (float*)(ws + oXN);               // alias (XN dead after qkv GEMM): 11,010,048 B
    float* Np           = (float*)(ws + oXN + 11010048);    // 344,064 B
    unsigned short* XCA = (unsigned short*)(ws + oXN);      // alias (Gp/Np dead after k_sm)
    unsigned short* Qb  = (unsigned short*)(ws + oQ);
    unsigned short* X2p = (unsigned short*)(ws + oQ);   // alias (Qb+Kb dead after k_qk); 41,336,832 B padded
    unsigned short* Kb  = (unsigned short*)(ws + oK);
    unsigned short* Vt  = (unsigned short*)(ws + oV);
    unsigned short* ATT = (unsigned short*)(ws + oATT);
    unsigned short* Wq  = (unsigned short*)(ws + oWq);
    unsigned short* Wp  = (unsigned short*)(ws + oWp);
    unsigned short* Wc  = (unsigned short*)(ws + oWc);

    kw_convert<<<256, 256, 0, stream>>>(qkv_w, proj_w, conv_w, Wq, Wp, Wc);
    k_pos<<<NN, 128, 0, stream>>>(pos_w, pos_b, P);
    k_tln<<<BB*98, 256, 0, stream>>>(x, P, ln_g, ln_b, XT, XN);
    k_gemm<0><<<3528, 256, 0, stream>>>(XN, Wq, qkv_b,
        Qb, Kb, Vt, nullptr, nullptr, nullptr);
    k_qk<<<dim3(7, BH), 256, 0, stream>>>(Qb, Kb, Gp, Np);
    k_sm<<<BH, 256, 0, stream>>>(Gp, Np, temp, rpb, ATT);
    // Q/K dead now; zero the padded X2 buffer (pad ring must be 0)
    hipMemsetAsync(X2p, 0, (size_t)BB*NP*DIM*2, stream);
    k_pv<<<dim3(49, BH), 256, 0, stream>>>(ATT, Vt, XCA);
    k_gemm<1><<<1176, 256, 0, stream>>>(XCA, Wp, proj_b,
        nullptr, nullptr, nullptr, XT, gxca, X2p);
    k_conv<<<1200, 256, 0, stream>>>(X2p, Wc, bn_g, bn_b, bn_mean, bn_var, Y);
    k_final<<<dim3(56, BB, 2), 256, 0, stream>>>(x, Y, gamma, out);
}

// Round 6
// 505.776 us; speedup vs baseline: 1.5278x; 1.0508x over previous
//
#include <hip/hip_runtime.h>
#include <hip/hip_bf16.h>
#include <math.h>

#define DIM 384
#define HEADS 6
#define NN 3136
#define BB 16
#define BH (BB*HEADS)
#define HP 58
#define NP (HP*HP)   // 3364 padded image

typedef __attribute__((ext_vector_type(8))) short short8;
typedef __attribute__((ext_vector_type(4))) short short4v;
typedef __attribute__((ext_vector_type(4))) float f32x4;

__device__ __forceinline__ float bf2f(unsigned short u) {
    union { unsigned int i; float f; } v; v.i = ((unsigned int)u) << 16; return v.f;
}
__device__ __forceinline__ unsigned short f2bf(float f) {
    union { float f; unsigned int i; } v; v.f = f;
    unsigned int r = v.i + 0x7fffu + ((v.i >> 16) & 1u);
    return (unsigned short)(r >> 16);
}
__device__ __forceinline__ void glds16(const unsigned short* g, void* l) {
    __builtin_amdgcn_global_load_lds(
        (const __attribute__((address_space(1))) unsigned int*)g,
        (__attribute__((address_space(3))) unsigned int*)l, 16, 0, 0);
}

// ---------------- weight conversion / rearrange ----------------
__global__ void kw_convert(const float* __restrict__ qkv_w, const float* __restrict__ proj_w,
                           const float* __restrict__ conv_w,
                           unsigned short* __restrict__ Wq, unsigned short* __restrict__ Wp,
                           unsigned short* __restrict__ Wc) {
    int tid = blockIdx.x * 256 + threadIdx.x;
    int stride = gridDim.x * 256;
    for (int i = tid; i < 3*DIM*DIM; i += stride) Wq[i] = f2bf(qkv_w[i]);
    for (int i = tid; i < DIM*DIM; i += stride) Wp[i] = f2bf(proj_w[i]);
    for (int i = tid; i < DIM*DIM*9; i += stride) {
        // dst layout: [o][tap][i]   src: (o, i, ky, kx) -> (o*384+i)*9 + tap
        int ii = i % DIM; int rest = i / DIM; int tap = rest % 9; int o = rest / 9;
        Wc[i] = f2bf(conv_w[(size_t)(o*DIM + ii)*9 + tap]);
    }
}

// ---------------- positional encoding table P[n][c] ----------------
__global__ void k_pos(const float* __restrict__ pos_w, const float* __restrict__ pos_b,
                      float* __restrict__ P) {
    int n = blockIdx.x; int h = n / 56, w = n % 56;
    __shared__ float feat[64];
    int t = threadIdx.x;
    if (t < 64) {
        int axis = t >> 5;      // 0 = y (h), 1 = x (w)
        int k = t & 31; int i = k >> 1;
        float e = (float)((axis ? w : h) + 1) / 56.000001f * 6.28318530717958647692f;
        float arg = e / powf(10000.0f, (float)i / 16.0f);
        feat[t] = (k & 1) ? cosf(arg) : sinf(arg);
    }
    __syncthreads();
    for (int c = t; c < DIM; c += blockDim.x) {
        float s = pos_b[c];
        #pragma unroll 8
        for (int k = 0; k < 64; k++) s += feat[k] * pos_w[c*64 + k];
        P[(size_t)n*DIM + c] = s;
    }
}

// ---------------- fused transpose + pos add + layernorm ----------------
// XTb bf16 (residual for proj epilogue) + XN bf16 (LN output)
__global__ __launch_bounds__(256) void k_tln(const float* __restrict__ x, const float* __restrict__ P,
                                             const float* __restrict__ g, const float* __restrict__ be,
                                             unsigned short* __restrict__ XTb, unsigned short* __restrict__ XN) {
    __shared__ float tile[32][388];
    int blk = blockIdx.x;
    int b = blk / 98, nt = blk % 98;
    int n0 = nt*32;
    int t = threadIdx.x;
    #pragma unroll
    for (int it = 0; it < 12; it++) {
        int task = it*256 + t;
        int c = task >> 3, seg = task & 7;
        float4 v = *reinterpret_cast<const float4*>(x + ((size_t)(b*DIM + c))*NN + n0 + seg*4);
        tile[seg*4+0][c] = v.x; tile[seg*4+1][c] = v.y;
        tile[seg*4+2][c] = v.z; tile[seg*4+3][c] = v.w;
    }
    __syncthreads();
    int row = t >> 3, sub = t & 7;
    int n = n0 + row;
    f32x4 xp[12];
    float s = 0.f;
    #pragma unroll
    for (int k = 0; k < 12; k++) {
        int c0 = (k*8 + sub)*4;
        float4 tv = *reinterpret_cast<float4*>(&tile[row][c0]);
        float4 pv = *reinterpret_cast<const float4*>(P + (size_t)n*DIM + c0);
        f32x4 xv = {tv.x+pv.x, tv.y+pv.y, tv.z+pv.z, tv.w+pv.w};
        xp[k] = xv;
        s += xv[0]+xv[1]+xv[2]+xv[3];
        unsigned short pkx[4];
        #pragma unroll
        for (int e=0;e<4;e++) pkx[e] = f2bf(xv[e]);
        *reinterpret_cast<short4v*>(XTb + ((size_t)(b*NN + n))*DIM + c0) = *(short4v*)pkx;
    }
    s += __shfl_xor(s, 1, 64); s += __shfl_xor(s, 2, 64); s += __shfl_xor(s, 4, 64);
    float mean = s * (1.0f/384.0f);
    float sq = 0.f;
    #pragma unroll
    for (int k = 0; k < 12; k++) {
        #pragma unroll
        for (int e = 0; e < 4; e++) { float d = xp[k][e]-mean; sq += d*d; }
    }
    sq += __shfl_xor(sq, 1, 64); sq += __shfl_xor(sq, 2, 64); sq += __shfl_xor(sq, 4, 64);
    float rs = rsqrtf(sq * (1.0f/384.0f) + 1e-6f);
    #pragma unroll
    for (int k = 0; k < 12; k++) {
        int c0 = (k*8 + sub)*4;
        unsigned short pk[4];
        #pragma unroll
        for (int e = 0; e < 4; e++)
            pk[e] = f2bf((xp[k][e]-mean)*rs*g[c0+e] + be[c0+e]);
        *reinterpret_cast<short4v*>(XN + ((size_t)(b*NN + n))*DIM + c0) = *(short4v*)pk;
    }
}

// ---------------- MFMA GEMM (K=384): MODE 0 = qkv, 1 = proj ----------------
// A+B double-buffered via swizzled global_load_lds, 1 barrier per k-step.
template<int MODE>
__global__ __launch_bounds__(256) void k_gemm(
    const unsigned short* __restrict__ A, const unsigned short* __restrict__ Wt,
    const float* __restrict__ bias,
    unsigned short* __restrict__ Qb, unsigned short* __restrict__ Kb, unsigned short* __restrict__ Vt,
    const unsigned short* __restrict__ XTb, const float* __restrict__ gxca, unsigned short* __restrict__ X2p)
{
    __shared__ __align__(16) char smem[35328];
    auto ctA = (float(*)[69])smem;                     // [128][69] 35328  ([o][m])
    auto ctB = (float(*)[130])smem;                    // [64][130] 33280  ([m][o])

    constexpr int NCT = (MODE == 0) ? 9 : 3;
    constexpr int CPX = (MODE == 0) ? 441 : 147;       // 392*NCT/8
    int bid = blockIdx.x;
    int orig = (bid & 7)*CPX + (bid >> 3);
    int ct = orig % NCT, mt = orig / NCT;
    int m0 = mt*128, o0 = ct*128;
    int t = threadIdx.x;
    int wave = t >> 6, lane = t & 63;
    int wr = wave >> 1, wc = wave & 1;
    int lr = lane & 15, lg = lane >> 4;

    // staging: source col pre-swizzled (both-sides rule for global_load_lds)
    int r0 = t >> 2;
    int swcol = (((t & 3) ^ ((t >> 3) & 3)) << 3);
    const unsigned short* a0 = A  + (size_t)(m0 + r0)*384 + swcol;
    const unsigned short* a1 = A  + (size_t)(m0 + 64 + r0)*384 + swcol;
    const unsigned short* b0 = Wt + (size_t)(o0 + r0)*384 + swcol;
    const unsigned short* b1 = Wt + (size_t)(o0 + 64 + r0)*384 + swcol;
    int rsw = ((lr >> 1) & 3) << 3;    // read-side swizzle (shorts)

    auto stage = [&](char* base, int c) {
        glds16(a0 + c, base + wave*1024);
        glds16(a1 + c, base + 4096 + wave*1024);
        glds16(b0 + c, base + 8192 + wave*1024);
        glds16(b1 + c, base + 12288 + wave*1024);
    };

    f32x4 acc[4][4];
    #pragma unroll
    for (int i=0;i<4;i++) for (int j=0;j<4;j++) acc[i][j] = (f32x4){0.f,0.f,0.f,0.f};

    stage(smem, 0);
    __syncthreads();
    for (int kk = 0; kk < 12; kk++) {
        if (kk < 11) stage(smem + ((kk+1)&1)*16384, (kk+1)*32);
        auto As = (unsigned short(*)[32])(smem + (kk&1)*16384);
        auto Bs = (unsigned short(*)[32])(smem + (kk&1)*16384 + 8192);
        short8 af[4], bfv[4];
        #pragma unroll
        for (int i=0;i<4;i++) af[i]  = *(short8*)&As[wr*64 + i*16 + lr][(lg*8) ^ rsw];
        #pragma unroll
        for (int j=0;j<4;j++) bfv[j] = *(short8*)&Bs[wc*64 + j*16 + lr][(lg*8) ^ rsw];
        #pragma unroll
        for (int i=0;i<4;i++)
            #pragma unroll
            for (int j=0;j<4;j++)
                acc[i][j] = __builtin_amdgcn_mfma_f32_16x16x32_bf16(af[i], bfv[j], acc[i][j], 0, 0, 0);
        __syncthreads();
    }

    // ---- epilogue ----
    int comp = (MODE == 0) ? (o0 / DIM) : 0;
    for (int mh = 0; mh < 2; mh++) {
        __syncthreads();
        bool useB = (MODE == 1) || (MODE == 0 && comp == 2);
        if (wr == mh) {
            if (useB) {
                #pragma unroll
                for (int i=0;i<4;i++) for (int j=0;j<4;j++) for (int r=0;r<4;r++)
                    ctB[i*16 + lg*4 + r][wc*64 + j*16 + lr] = acc[i][j][r];
            } else {
                #pragma unroll
                for (int i=0;i<4;i++) for (int j=0;j<4;j++) for (int r=0;r<4;r++)
                    ctA[wc*64 + j*16 + lr][i*16 + lg*4 + r] = acc[i][j][r];
            }
        }
        __syncthreads();
        if (MODE == 1) {
            for (int q = t; q < 1024; q += 256) {   // 64 m-rows x 16 o-segs(8)
                int row = q >> 4, seg = q & 15;
                int m = m0 + mh*64 + row; int b = m/NN; int n = m - b*NN;
                int py = n/56, px = n - py*56;
                int og0 = o0 + seg*8;
                short8 xvb = *(const short8*)(XTb + (size_t)m*DIM + og0);
                unsigned short pk[8];
                #pragma unroll
                for (int e=0;e<8;e++) {
                    float val = ctB[row][seg*8+e] + bias[og0+e];
                    pk[e] = f2bf(bf2f((unsigned short)xvb[e]) + gxca[og0+e]*val);
                }
                *(short8*)(X2p + ((size_t)(b*NP + (py+1)*HP + px + 1))*DIM + og0) = *(short8*)pk;
            }
        } else if (comp < 2) {                      // Q / K: (bh,dd,N) layout
            unsigned short* Dst = (comp == 0) ? Qb : Kb;
            for (int q = t; q < 2048; q += 256) {   // 128 o-rows x 16 m-segs(4)
                int row = q >> 4, seg = q & 15;
                int og = o0 + row; int rem = og - comp*DIM;
                int hh = rem >> 6, dd = rem & 63;
                int m4 = m0 + mh*64 + seg*4; int b = m4/NN; int n = m4 - b*NN;
                float bv = bias[og];
                unsigned short pk[4];
                #pragma unroll
                for (int e=0;e<4;e++) pk[e] = f2bf(ctA[row][seg*4+e] + bv);
                *(short4v*)(Dst + ((size_t)((b*HEADS + hh)*64 + dd))*NN + n) = *(short4v*)pk;
            }
        } else {                                    // V: (bh,N,dd) layout
            for (int q = t; q < 1024; q += 256) {   // 64 m-rows x 16 o-segs(8)
                int row = q >> 4, seg = q & 15;
                int m = m0 + mh*64 + row; int b = m/NN; int n = m - b*NN;
                int og0 = o0 + seg*8; int rem0 = og0 - 2*DIM;
                int hh = rem0 >> 6, dd0 = rem0 & 63;
                unsigned short pk[8];
                #pragma unroll
                for (int e=0;e<8;e++) pk[e] = f2bf(ctB[row][seg*8+e] + bias[og0+e]);
                *(short8*)(Vt + ((size_t)((b*HEADS + hh)*NN + n))*64 + dd0) = *(short8*)pk;
            }
        }
    }
}

// ---------------- pad-ring zero for X2p (replaces 41MB memset) ----------------
__global__ __launch_bounds__(256) void k_pad(unsigned short* __restrict__ X2p) {
    int b = blockIdx.x, part = blockIdx.y;   // grid (16, 8)
    unsigned short* base = X2p + (size_t)b*NP*DIM;
    short8 z = {0,0,0,0,0,0,0,0};
    // 228 pad positions x 48 segs(8) = 10944 tasks split across 8 parts
    for (int task = part*256 + threadIdx.x; task < 10944; task += 2048) {
        int pos = task / 48, seg = task - pos*48;
        int py, px;
        if (pos < 58)       { py = 0;  px = pos; }
        else if (pos < 116) { py = 57; px = pos - 58; }
        else if (pos < 172) { py = pos - 115; px = 0; }
        else                { py = pos - 171; px = 57; }
        *(short8*)(base + ((size_t)(py*HP + px))*DIM + seg*8) = z;
    }
}

// ---------------- conv3x3 + BN + SiLU + residual, 8-wave blocks ----------------
// A-halo single-buffer + B tap-double-buffer, swizzled glds staging.
// Wave grid: 2(m-half 64) x 4(o-quarter 32); acc[4][2] = 32 AGPR/wave.
__global__ __launch_bounds__(512) void k_conv(
    const unsigned short* __restrict__ A, const unsigned short* __restrict__ Wt,
    const float* __restrict__ bn_g, const float* __restrict__ bn_b,
    const float* __restrict__ bn_mean, const float* __restrict__ bn_var,
    float* __restrict__ Yout)
{
    __shared__ __align__(16) char smem[32768];
    // k-loop: A halo [256][32] @0 (16KB), B dbuf 2x[128][32] @16384
    auto ctA = (float(*)[69])smem;                     // [64][69] 17664
    auto X2s = (unsigned short(*)[68])(smem + 17664);  // [64][68] 8704

    int bid = blockIdx.x;                 // 1200 = 8*150
    int orig = (bid & 7)*150 + (bid >> 3);
    int ct = orig % 3; int rest = orig / 3;
    int tile = rest % 25; int b = rest / 25;
    int n0 = tile*128, o0 = ct*128;
    int t = threadIdx.x;
    int wave = t >> 6, lane = t & 63;
    int wr = wave >> 2, wc = wave & 3;
    int lr = lane & 15, lg = lane >> 4;
    int qb = n0 + 2*(n0/56);
    const size_t bbase = (size_t)b*NP*DIM;

    int swcol = (((t & 3) ^ ((t >> 3) & 3)) << 3);
    // A-halo: 1024 tasks = 2/thread (task = j*512 + t)
    const unsigned short* asrc[2];
    #pragma unroll
    for (int j=0;j<2;j++) {
        int row = j*128 + (t >> 2);
        int q = qb + row; if (q > NP-1) q = NP-1;
        asrc[j] = A + bbase + (size_t)q*DIM + swcol;
    }
    // B: 512 tasks = 1/thread
    const unsigned short* bsrc = Wt + (size_t)(o0 + (t >> 2))*3456 + swcol;

    // per-lane MFMA A row offsets (position-relative)
    int qrel[4];
    #pragma unroll
    for (int i=0;i<4;i++) {
        int loc = wr*64 + i*16 + lr;
        int n = n0 + loc; if (n >= NN) n = NN-1;
        qrel[i] = n + 2*(n/56) - qb;
    }

    auto stageA = [&](int c) {
        #pragma unroll
        for (int j=0;j<2;j++) glds16(asrc[j] + c, smem + j*8192 + wave*1024);
    };
    auto stageB = [&](char* base, int off) {
        glds16(bsrc + off, base + wave*1024);
    };

    f32x4 acc[4][2];
    #pragma unroll
    for (int i=0;i<4;i++) for (int j=0;j<2;j++) acc[i][j] = (f32x4){0.f,0.f,0.f,0.f};

    stageA(0); stageB(smem + 16384, 0);
    __syncthreads();
    for (int kk = 0; kk < 12; kk++) {
        int c = kk*32;
        auto Ah = (unsigned short(*)[32])smem;
        #pragma unroll
        for (int tap = 0; tap < 9; tap++) {
            int buf = tap & 1;
            if (tap < 8) stageB(smem + 16384 + (buf^1)*8192, (tap+1)*384 + c);
            auto Bs = (unsigned short(*)[32])(smem + 16384 + buf*8192);
            int toff = (tap/3)*58 + (tap%3);
            short8 af[4], bfv[2];
            #pragma unroll
            for (int j=0;j<2;j++) {
                int brow = wc*32 + j*16 + lr;
                bfv[j] = *(short8*)&Bs[brow][(lg*8) ^ (((brow>>1)&3)<<3)];
            }
            #pragma unroll
            for (int i=0;i<4;i++) {
                int row = qrel[i] + toff;
                af[i] = *(short8*)&Ah[row][(lg*8) ^ (((row>>1)&3)<<3)];
            }
            #pragma unroll
            for (int i=0;i<4;i++)
                #pragma unroll
                for (int j=0;j<2;j++)
                    acc[i][j] = __builtin_amdgcn_mfma_f32_16x16x32_bf16(af[i], bfv[j], acc[i][j], 0, 0, 0);
            __syncthreads();
        }
        if (kk < 11) {
            stageA(c + 32);
            stageB(smem + 16384, c + 32);   // (kk+1, tap0) into buf0
            __syncthreads();
        }
    }

    // ---- epilogue: 4 quadrant passes (mh x oh), coalesced float4 writes ----
    for (int mh = 0; mh < 2; mh++) {
        for (int oh = 0; oh < 2; oh++) {
            __syncthreads();
            if (wr == mh && (wc >> 1) == oh) {
                #pragma unroll
                for (int i=0;i<4;i++) for (int j=0;j<2;j++) for (int r=0;r<4;r++)
                    ctA[(wc&1)*32 + j*16 + lr][i*16 + lg*4 + r] = acc[i][j][r];
            }
            {   // residual: 512 tasks = 1/thread (64 m-rows x 8 o-segs(8))
                int row = t >> 3, sg = t & 7;
                int n = n0 + mh*64 + row; int nc = (n < NN) ? n : NN-1;
                int qq = nc + 2*(nc/56) + 59;       // center tap (+1,+1)
                short8 v = *(const short8*)(A + bbase + (size_t)qq*DIM + o0 + oh*64 + sg*8);
                short4v lo = {v[0],v[1],v[2],v[3]}, hi = {v[4],v[5],v[6],v[7]};
                *(short4v*)&X2s[row][sg*8]     = lo;
                *(short4v*)&X2s[row][sg*8 + 4] = hi;
            }
            __syncthreads();
            for (int q = t; q < 1024; q += 512) {   // 64 o-rows x 16 m-segs(4)
                int orow = q >> 4, sg = q & 15;
                int o = o0 + oh*64 + orow;
                int n = n0 + mh*64 + sg*4;
                if (n < NN) {
                    float mean = bn_mean[o], rs = rsqrtf(bn_var[o] + 1e-5f);
                    float gg = bn_g[o], bb2 = bn_b[o];
                    float4 ov; float* po = &ov.x;
                    #pragma unroll
                    for (int e=0;e<4;e++) {
                        float xi = (ctA[orow][sg*4+e] - mean)*rs*gg + bb2;
                        float si = xi / (1.0f + __expf(-xi));
                        po[e] = si + bf2f(X2s[sg*4+e][orow]);
                    }
                    *(float4*)(Yout + ((size_t)(b*DIM + o))*NN + n) = ov;
                }
            }
        }
    }
}

// ---------------- attention stage 1: partial G = q k^T + partial sq-norms ----------------
// grid (7 chunks, 96 bh); chunk = 448 columns (3136 = 7*448)
__global__ __launch_bounds__(256) void k_qk(const unsigned short* __restrict__ Qb,
                                            const unsigned short* __restrict__ Kb,
                                            float* __restrict__ Gp, float* __restrict__ Np) {
    int cx = blockIdx.x, bh = blockIdx.y;
    int t = threadIdx.x, wave = t >> 6, lane = t & 63;
    int lr = lane & 15, lg = lane >> 4;
    {   // partial squared norms: 128 rows x 2 threads
        int row = t >> 1, p = t & 1;
        const unsigned short* src = (row < 64)
            ? Qb + ((size_t)bh*64 + row)*NN + cx*448
            : Kb + ((size_t)bh*64 + (row-64))*NN + cx*448;
        float s = 0.f;
        #pragma unroll
        for (int it = 0; it < 28; it++) {
            short8 v = *(const short8*)(src + p*224 + it*8);
            #pragma unroll
            for (int jj=0;jj<8;jj++) { float f = bf2f((unsigned short)v[jj]); s += f*f; }
        }
        s += __shfl_xor(s, 1, 64);
        if (p == 0) Np[((size_t)bh*7 + cx)*128 + row] = s;
    }
    f32x4 acc[4];
    #pragma unroll
    for (int j=0;j<4;j++) acc[j] = (f32x4){0.f,0.f,0.f,0.f};
    const unsigned short* qrow = Qb + ((size_t)bh*64 + wave*16 + lr)*NN + cx*448;
    const unsigned short* kbase = Kb + (size_t)bh*64*NN + cx*448;
    for (int ks = 0; ks < 14; ks++) {
        short8 a = *(const short8*)(qrow + ks*32 + lg*8);
        #pragma unroll
        for (int j=0;j<4;j++) {
            short8 bfr = *(const short8*)(kbase + (size_t)(j*16+lr)*NN + ks*32 + lg*8);
            acc[j] = __builtin_amdgcn_mfma_f32_16x16x32_bf16(a, bfr, acc[j], 0, 0, 0);
        }
    }
    float* gbase = Gp + ((size_t)bh*7 + cx)*4096;
    #pragma unroll
    for (int j=0;j<4;j++)
        #pragma unroll
        for (int r=0;r<4;r++)
            gbase[(wave*16 + lg*4 + r)*64 + j*16 + lr] = acc[j][r];
}

// ---------------- attention stage 2: combine + normalize + softmax -> ATT ----------------
__global__ __launch_bounds__(256) void k_sm(const float* __restrict__ Gp, const float* __restrict__ Np,
                                            const float* __restrict__ temperature,
                                            const float* __restrict__ rpb,
                                            unsigned short* __restrict__ ATT) {
    int bh = blockIdx.x; int h = bh % HEADS;
    int t = threadIdx.x;
    __shared__ float snorm[128];
    if (t < 128) {
        float s = 0.f;
        #pragma unroll
        for (int cx=0;cx<7;cx++) s += Np[((size_t)bh*7 + cx)*128 + t];
        snorm[t] = fmaxf(sqrtf(s), 1e-12f);
    }
    __syncthreads();
    int dq = t >> 2, de0 = (t & 3) * 16;
    f32x4 g[4];
    #pragma unroll
    for (int i=0;i<4;i++) g[i] = (f32x4){0.f,0.f,0.f,0.f};
    #pragma unroll
    for (int cx=0;cx<7;cx++) {
        const float* base = Gp + ((size_t)bh*7 + cx)*4096 + dq*64 + de0;
        #pragma unroll
        for (int i=0;i<4;i++) {
            float4 v = *(const float4*)(base + i*4);
            g[i][0]+=v.x; g[i][1]+=v.y; g[i][2]+=v.z; g[i][3]+=v.w;
        }
    }
    float temp = temperature[h];
    float bias = rpb[HEADS + h];
    float qn = snorm[dq];
    float lv[16]; float mx = -1e30f;
    #pragma unroll
    for (int i=0;i<4;i++)
        #pragma unroll
        for (int e=0;e<4;e++) {
            int de = de0 + i*4 + e;
            float v = g[i][e] / (qn * snorm[64 + de]) * temp + bias;
            lv[i*4+e] = v; mx = fmaxf(mx, v);
        }
    mx = fmaxf(mx, __shfl_xor(mx, 1, 64));
    mx = fmaxf(mx, __shfl_xor(mx, 2, 64));
    float se = 0.f;
    #pragma unroll
    for (int e=0;e<16;e++) { lv[e] = __expf(lv[e]-mx); se += lv[e]; }
    se += __shfl_xor(se, 1, 64);
    se += __shfl_xor(se, 2, 64);
    float inv = 1.0f/se;
    unsigned short pk[16];
    #pragma unroll
    for (int e=0;e<16;e++) pk[e] = f2bf(lv[e]*inv);
    unsigned short* dst = ATT + ((size_t)bh*64 + dq)*64 + de0;
    *(short8*)dst       = *(short8*)pk;
    *(short8*)(dst + 8) = *(short8*)(pk + 8);
}

// ---------------- PV: XCA[b][n][h*64+dd] = sum_e ATT[dd][e] * V[e][n] ----------------
__global__ __launch_bounds__(256) void k_pv(const unsigned short* __restrict__ ATT,
                                            const unsigned short* __restrict__ Vt,
                                            unsigned short* __restrict__ XCA) {
    int nt = blockIdx.x, bh = blockIdx.y;
    int b = bh / HEADS, h = bh % HEADS;
    int t = threadIdx.x, wave = t >> 6, lane = t & 63;
    int lr = lane & 15, lg = lane >> 4;
    int n0 = nt*64;
    __shared__ float ctP[64][67];
    f32x4 acc[4];
    for (int i=0;i<4;i++) acc[i] = (f32x4){0.f,0.f,0.f,0.f};
    for (int ks=0; ks<2; ks++) {
        short8 bfr = *reinterpret_cast<const short8*>(Vt + ((size_t)bh*NN + n0 + wave*16 + lr)*64 + ks*32 + lg*8);
        for (int i=0;i<4;i++) {
            short8 a = *reinterpret_cast<const short8*>(ATT + ((size_t)bh*64 + i*16 + lr)*64 + ks*32 + lg*8);
            acc[i] = __builtin_amdgcn_mfma_f32_16x16x32_bf16(a, bfr, acc[i], 0, 0, 0);
        }
    }
    int nl = wave*16 + lr;
    #pragma unroll
    for (int i=0;i<4;i++)
        #pragma unroll
        for (int r=0;r<4;r++) ctP[nl][i*16 + lg*4 + r] = acc[i][r];
    __syncthreads();
    for (int q = t; q < 512; q += 256) {   // 64 n-rows x 8 dd-segs(8)
        int row = q >> 3, seg = q & 7;
        unsigned short pk[8];
        #pragma unroll
        for (int e=0;e<8;e++) pk[e] = f2bf(ctP[row][seg*8+e]);
        *(short8*)(XCA + ((size_t)(b*NN + n0 + row))*DIM + h*64 + seg*8) = *(short8*)pk;
    }
}

// ---------------- final: out = x + gamma-shuffled residual ----------------
__global__ __launch_bounds__(256) void k_final(const float* __restrict__ x, const float* __restrict__ Y,
                                               const float* __restrict__ gamma, float* __restrict__ out) {
    int i = blockIdx.x, b = blockIdx.y, kc = blockIdx.z;
    __shared__ float tile[56*193];
    int t = threadIdx.x;
    int k0 = kc*192;
    const float* ybase = Y + (size_t)b*DIM*NN + (size_t)i*21504 + k0;
    for (int q = t; q < 56*48; q += 256) {
        int j = q / 48, c4 = (q % 48) * 4;
        float4 v = *reinterpret_cast<const float4*>(ybase + (size_t)j*384 + c4);
        float* dst = &tile[j*193 + c4];
        dst[0]=v.x; dst[1]=v.y; dst[2]=v.z; dst[3]=v.w;
    }
    __syncthreads();
    for (int q = t; q < 192*56; q += 256) {
        int kl = q / 56, j = q % 56;
        int k = k0 + kl;
        size_t gi = ((size_t)(b*DIM + k))*NN + (size_t)i*56 + j;
        out[gi] = x[gi] + gamma[k] * tile[j*193 + kl];
    }
}

extern "C" void kernel_launch(void* const* d_in, const int* in_sizes, int n_in,
                              void* d_out, int out_size, void* d_ws, size_t ws_size,
                              hipStream_t stream) {
    const float* x       = (const float*)d_in[0];
    const float* pos_w   = (const float*)d_in[1];
    const float* pos_b   = (const float*)d_in[2];
    const float* ln_g    = (const float*)d_in[3];
    const float* ln_b    = (const float*)d_in[4];
    const float* gxca    = (const float*)d_in[5];
    const float* temp    = (const float*)d_in[6];
    const float* qkv_w   = (const float*)d_in[7];
    const float* qkv_b   = (const float*)d_in[8];
    const float* proj_w  = (const float*)d_in[9];
    const float* proj_b  = (const float*)d_in[10];
    const float* rpb     = (const float*)d_in[11];
    const float* conv_w  = (const float*)d_in[12];
    const float* bn_g    = (const float*)d_in[13];
    const float* bn_b    = (const float*)d_in[14];
    const float* bn_mean = (const float*)d_in[15];
    const float* bn_var  = (const float*)d_in[16];
    const float* gamma   = (const float*)d_in[17];
    float* out = (float*)d_out;
    char* ws = (char*)d_ws;

    const size_t oP   = 0;                        // P: 4,816,896 B
    const size_t oXT  = oP   + 4816896;           // XTb bf16 (38.5MB); region also holds Y fp32 (77MB)
    const size_t oXN  = oXT  + 77070336;          // XN bf16: 38,535,168 B   (reused as Gp/Np, then XCA)
    const size_t oQ   = oXN  + 38535168;          // Qb bf16                  (reused as X2p padded, spans into Kb)
    const size_t oK   = oQ   + 38535168;          // Kb bf16
    const size_t oV   = oK   + 38535168;          // Vt bf16
    const size_t oATT = oV   + 38535168;          // ATT bf16: 786,432 B
    const size_t oWq  = oATT + 786432;            // 884,736 B
    const size_t oWp  = oWq  + 884736;            // 294,912 B
    const size_t oWc  = oWp  + 294912;            // 2,654,208 B

    float* P            = (float*)(ws + oP);
    unsigned short* XTb = (unsigned short*)(ws + oXT);
    float* Y            = (float*)(ws + oXT);     // alias (XTb dead after proj epilogue)
    unsigned short* XN  = (unsigned short*)(ws + oXN);
    float* Gp           = (float*)(ws + oXN);               // alias (XN dead after qkv GEMM): 11,010,048 B
    float* Np           = (float*)(ws + oXN + 11010048);    // 344,064 B
    unsigned short* XCA = (unsigned short*)(ws + oXN);      // alias (Gp/Np dead after k_sm)
    unsigned short* Qb  = (unsigned short*)(ws + oQ);
    unsigned short* X2p = (unsigned short*)(ws + oQ);   // alias (Qb+Kb dead after k_qk); 41,336,832 B padded
    unsigned short* Kb  = (unsigned short*)(ws + oK);
    unsigned short* Vt  = (unsigned short*)(ws + oV);
    unsigned short* ATT = (unsigned short*)(ws + oATT);
    unsigned short* Wq  = (unsigned short*)(ws + oWq);
    unsigned short* Wp  = (unsigned short*)(ws + oWp);
    unsigned short* Wc  = (unsigned short*)(ws + oWc);

    kw_convert<<<256, 256, 0, stream>>>(qkv_w, proj_w, conv_w, Wq, Wp, Wc);
    k_pos<<<NN, 128, 0, stream>>>(pos_w, pos_b, P);
    k_tln<<<BB*98, 256, 0, stream>>>(x, P, ln_g, ln_b, XTb, XN);
    k_gemm<0><<<3528, 256, 0, stream>>>(XN, Wq, qkv_b,
        Qb, Kb, Vt, nullptr, nullptr, nullptr);
    k_qk<<<dim3(7, BH), 256, 0, stream>>>(Qb, Kb, Gp, Np);
    k_sm<<<BH, 256, 0, stream>>>(Gp, Np, temp, rpb, ATT);
    // Q/K dead now; zero only the pad ring of X2p (interior fully written by proj epilogue)
    k_pad<<<dim3(BB, 8), 256, 0, stream>>>(X2p);
    k_pv<<<dim3(49, BH), 256, 0, stream>>>(ATT, Vt, XCA);
    k_gemm<1><<<1176, 256, 0, stream>>>(XCA, Wp, proj_b,
        nullptr, nullptr, nullptr, XTb, gxca, X2p);
    k_conv<<<1200, 512, 0, stream>>>(X2p, Wc, bn_g, bn_b, bn_mean, bn_var, Y);
    k_final<<<dim3(56, BB, 2), 256, 0, stream>>>(x, Y, gamma, out);
}

// Round 7
// 474.105 us; speedup vs baseline: 1.6299x; 1.0668x over previous
//
#include <hip/hip_runtime.h>
#include <hip/hip_bf16.h>
#include <math.h>

#define DIM 384
#define HEADS 6
#define NN 3136
#define BB 16
#define BH (BB*HEADS)
#define HP 58
#define NP (HP*HP)   // 3364 padded image

typedef __attribute__((ext_vector_type(8))) short short8;
typedef __attribute__((ext_vector_type(4))) short short4v;
typedef __attribute__((ext_vector_type(4))) float f32x4;

__device__ __forceinline__ float bf2f(unsigned short u) {
    union { unsigned int i; float f; } v; v.i = ((unsigned int)u) << 16; return v.f;
}
__device__ __forceinline__ unsigned short f2bf(float f) {
    union { float f; unsigned int i; } v; v.f = f;
    unsigned int r = v.i + 0x7fffu + ((v.i >> 16) & 1u);
    return (unsigned short)(r >> 16);
}
__device__ __forceinline__ void glds16(const unsigned short* g, void* l) {
    __builtin_amdgcn_global_load_lds(
        (const __attribute__((address_space(1))) unsigned int*)g,
        (__attribute__((address_space(3))) unsigned int*)l, 16, 0, 0);
}

// ---------------- weight conversion / rearrange ----------------
__global__ void kw_convert(const float* __restrict__ qkv_w, const float* __restrict__ proj_w,
                           const float* __restrict__ conv_w,
                           unsigned short* __restrict__ Wq, unsigned short* __restrict__ Wp,
                           unsigned short* __restrict__ Wc) {
    int tid = blockIdx.x * 256 + threadIdx.x;
    int stride = gridDim.x * 256;
    for (int i = tid; i < 3*DIM*DIM; i += stride) Wq[i] = f2bf(qkv_w[i]);
    for (int i = tid; i < DIM*DIM; i += stride) Wp[i] = f2bf(proj_w[i]);
    for (int i = tid; i < DIM*DIM*9; i += stride) {
        // dst layout: [o][tap][i]   src: (o, i, ky, kx) -> (o*384+i)*9 + tap
        int ii = i % DIM; int rest = i / DIM; int tap = rest % 9; int o = rest / 9;
        Wc[i] = f2bf(conv_w[(size_t)(o*DIM + ii)*9 + tap]);
    }
}

// ---------------- positional encoding table P[n][c] ----------------
__global__ void k_pos(const float* __restrict__ pos_w, const float* __restrict__ pos_b,
                      float* __restrict__ P) {
    int n = blockIdx.x; int h = n / 56, w = n % 56;
    __shared__ float feat[64];
    int t = threadIdx.x;
    if (t < 64) {
        int axis = t >> 5;      // 0 = y (h), 1 = x (w)
        int k = t & 31; int i = k >> 1;
        float e = (float)((axis ? w : h) + 1) / 56.000001f * 6.28318530717958647692f;
        float arg = e / powf(10000.0f, (float)i / 16.0f);
        feat[t] = (k & 1) ? cosf(arg) : sinf(arg);
    }
    __syncthreads();
    for (int c = t; c < DIM; c += blockDim.x) {
        float s = pos_b[c];
        #pragma unroll 8
        for (int k = 0; k < 64; k++) s += feat[k] * pos_w[c*64 + k];
        P[(size_t)n*DIM + c] = s;
    }
}

// ---------------- fused transpose + pos add + layernorm ----------------
// XTb bf16 (residual for proj epilogue) + XN bf16 (LN output)
__global__ __launch_bounds__(256) void k_tln(const float* __restrict__ x, const float* __restrict__ P,
                                             const float* __restrict__ g, const float* __restrict__ be,
                                             unsigned short* __restrict__ XTb, unsigned short* __restrict__ XN) {
    __shared__ float tile[32][388];
    int blk = blockIdx.x;
    int b = blk / 98, nt = blk % 98;
    int n0 = nt*32;
    int t = threadIdx.x;
    #pragma unroll
    for (int it = 0; it < 12; it++) {
        int task = it*256 + t;
        int c = task >> 3, seg = task & 7;
        float4 v = *reinterpret_cast<const float4*>(x + ((size_t)(b*DIM + c))*NN + n0 + seg*4);
        tile[seg*4+0][c] = v.x; tile[seg*4+1][c] = v.y;
        tile[seg*4+2][c] = v.z; tile[seg*4+3][c] = v.w;
    }
    __syncthreads();
    int row = t >> 3, sub = t & 7;
    int n = n0 + row;
    f32x4 xp[12];
    float s = 0.f;
    #pragma unroll
    for (int k = 0; k < 12; k++) {
        int c0 = (k*8 + sub)*4;
        float4 tv = *reinterpret_cast<float4*>(&tile[row][c0]);
        float4 pv = *reinterpret_cast<const float4*>(P + (size_t)n*DIM + c0);
        f32x4 xv = {tv.x+pv.x, tv.y+pv.y, tv.z+pv.z, tv.w+pv.w};
        xp[k] = xv;
        s += xv[0]+xv[1]+xv[2]+xv[3];
        unsigned short pkx[4];
        #pragma unroll
        for (int e=0;e<4;e++) pkx[e] = f2bf(xv[e]);
        *reinterpret_cast<short4v*>(XTb + ((size_t)(b*NN + n))*DIM + c0) = *(short4v*)pkx;
    }
    s += __shfl_xor(s, 1, 64); s += __shfl_xor(s, 2, 64); s += __shfl_xor(s, 4, 64);
    float mean = s * (1.0f/384.0f);
    float sq = 0.f;
    #pragma unroll
    for (int k = 0; k < 12; k++) {
        #pragma unroll
        for (int e = 0; e < 4; e++) { float d = xp[k][e]-mean; sq += d*d; }
    }
    sq += __shfl_xor(sq, 1, 64); sq += __shfl_xor(sq, 2, 64); sq += __shfl_xor(sq, 4, 64);
    float rs = rsqrtf(sq * (1.0f/384.0f) + 1e-6f);
    #pragma unroll
    for (int k = 0; k < 12; k++) {
        int c0 = (k*8 + sub)*4;
        unsigned short pk[4];
        #pragma unroll
        for (int e = 0; e < 4; e++)
            pk[e] = f2bf((xp[k][e]-mean)*rs*g[c0+e] + be[c0+e]);
        *reinterpret_cast<short4v*>(XN + ((size_t)(b*NN + n))*DIM + c0) = *(short4v*)pk;
    }
}

// ---------------- MFMA GEMM (K=384): MODE 0 = qkv, 1 = proj ----------------
// A+B double-buffered via swizzled global_load_lds, 1 barrier per k-step.
template<int MODE>
__global__ __launch_bounds__(256) void k_gemm(
    const unsigned short* __restrict__ A, const unsigned short* __restrict__ Wt,
    const float* __restrict__ bias,
    unsigned short* __restrict__ Qb, unsigned short* __restrict__ Kb, unsigned short* __restrict__ Vt,
    const unsigned short* __restrict__ XTb, const float* __restrict__ gxca, unsigned short* __restrict__ X2p)
{
    __shared__ __align__(16) char smem[35328];
    auto ctA = (float(*)[69])smem;                     // [128][69] 35328  ([o][m])
    auto ctB = (float(*)[130])smem;                    // [64][130] 33280  ([m][o])

    constexpr int NCT = (MODE == 0) ? 9 : 3;
    constexpr int CPX = (MODE == 0) ? 441 : 147;       // 392*NCT/8
    int bid = blockIdx.x;
    int orig = (bid & 7)*CPX + (bid >> 3);
    int ct = orig % NCT, mt = orig / NCT;
    int m0 = mt*128, o0 = ct*128;
    int t = threadIdx.x;
    int wave = t >> 6, lane = t & 63;
    int wr = wave >> 1, wc = wave & 1;
    int lr = lane & 15, lg = lane >> 4;

    // staging: source col pre-swizzled (both-sides rule for global_load_lds)
    int r0 = t >> 2;
    int swcol = (((t & 3) ^ ((t >> 3) & 3)) << 3);
    const unsigned short* a0 = A  + (size_t)(m0 + r0)*384 + swcol;
    const unsigned short* a1 = A  + (size_t)(m0 + 64 + r0)*384 + swcol;
    const unsigned short* b0 = Wt + (size_t)(o0 + r0)*384 + swcol;
    const unsigned short* b1 = Wt + (size_t)(o0 + 64 + r0)*384 + swcol;
    int rsw = ((lr >> 1) & 3) << 3;    // read-side swizzle (shorts)

    auto stage = [&](char* base, int c) {
        glds16(a0 + c, base + wave*1024);
        glds16(a1 + c, base + 4096 + wave*1024);
        glds16(b0 + c, base + 8192 + wave*1024);
        glds16(b1 + c, base + 12288 + wave*1024);
    };

    f32x4 acc[4][4];
    #pragma unroll
    for (int i=0;i<4;i++) for (int j=0;j<4;j++) acc[i][j] = (f32x4){0.f,0.f,0.f,0.f};

    stage(smem, 0);
    __syncthreads();
    for (int kk = 0; kk < 12; kk++) {
        if (kk < 11) stage(smem + ((kk+1)&1)*16384, (kk+1)*32);
        auto As = (unsigned short(*)[32])(smem + (kk&1)*16384);
        auto Bs = (unsigned short(*)[32])(smem + (kk&1)*16384 + 8192);
        short8 af[4], bfv[4];
        #pragma unroll
        for (int i=0;i<4;i++) af[i]  = *(short8*)&As[wr*64 + i*16 + lr][(lg*8) ^ rsw];
        #pragma unroll
        for (int j=0;j<4;j++) bfv[j] = *(short8*)&Bs[wc*64 + j*16 + lr][(lg*8) ^ rsw];
        #pragma unroll
        for (int i=0;i<4;i++)
            #pragma unroll
            for (int j=0;j<4;j++)
                acc[i][j] = __builtin_amdgcn_mfma_f32_16x16x32_bf16(af[i], bfv[j], acc[i][j], 0, 0, 0);
        __syncthreads();
    }

    // ---- epilogue ----
    int comp = (MODE == 0) ? (o0 / DIM) : 0;
    for (int mh = 0; mh < 2; mh++) {
        __syncthreads();
        bool useB = (MODE == 1) || (MODE == 0 && comp == 2);
        if (wr == mh) {
            if (useB) {
                #pragma unroll
                for (int i=0;i<4;i++) for (int j=0;j<4;j++) for (int r=0;r<4;r++)
                    ctB[i*16 + lg*4 + r][wc*64 + j*16 + lr] = acc[i][j][r];
            } else {
                #pragma unroll
                for (int i=0;i<4;i++) for (int j=0;j<4;j++) for (int r=0;r<4;r++)
                    ctA[wc*64 + j*16 + lr][i*16 + lg*4 + r] = acc[i][j][r];
            }
        }
        __syncthreads();
        if (MODE == 1) {
            for (int q = t; q < 1024; q += 256) {   // 64 m-rows x 16 o-segs(8)
                int row = q >> 4, seg = q & 15;
                int m = m0 + mh*64 + row; int b = m/NN; int n = m - b*NN;
                int py = n/56, px = n - py*56;
                int og0 = o0 + seg*8;
                short8 xvb = *(const short8*)(XTb + (size_t)m*DIM + og0);
                unsigned short pk[8];
                #pragma unroll
                for (int e=0;e<8;e++) {
                    float val = ctB[row][seg*8+e] + bias[og0+e];
                    pk[e] = f2bf(bf2f((unsigned short)xvb[e]) + gxca[og0+e]*val);
                }
                *(short8*)(X2p + ((size_t)(b*NP + (py+1)*HP + px + 1))*DIM + og0) = *(short8*)pk;
            }
        } else if (comp < 2) {                      // Q / K: (bh,dd,N) layout
            unsigned short* Dst = (comp == 0) ? Qb : Kb;
            for (int q = t; q < 2048; q += 256) {   // 128 o-rows x 16 m-segs(4)
                int row = q >> 4, seg = q & 15;
                int og = o0 + row; int rem = og - comp*DIM;
                int hh = rem >> 6, dd = rem & 63;
                int m4 = m0 + mh*64 + seg*4; int b = m4/NN; int n = m4 - b*NN;
                float bv = bias[og];
                unsigned short pk[4];
                #pragma unroll
                for (int e=0;e<4;e++) pk[e] = f2bf(ctA[row][seg*4+e] + bv);
                *(short4v*)(Dst + ((size_t)((b*HEADS + hh)*64 + dd))*NN + n) = *(short4v*)pk;
            }
        } else {                                    // V: (bh,N,dd) layout
            for (int q = t; q < 1024; q += 256) {   // 64 m-rows x 16 o-segs(8)
                int row = q >> 4, seg = q & 15;
                int m = m0 + mh*64 + row; int b = m/NN; int n = m - b*NN;
                int og0 = o0 + seg*8; int rem0 = og0 - 2*DIM;
                int hh = rem0 >> 6, dd0 = rem0 & 63;
                unsigned short pk[8];
                #pragma unroll
                for (int e=0;e<8;e++) pk[e] = f2bf(ctB[row][seg*8+e] + bias[og0+e]);
                *(short8*)(Vt + ((size_t)((b*HEADS + hh)*NN + n))*64 + dd0) = *(short8*)pk;
            }
        }
    }
}

// ---------------- pad-ring zero for X2p ----------------
__global__ __launch_bounds__(256) void k_pad(unsigned short* __restrict__ X2p) {
    int b = blockIdx.x, part = blockIdx.y;   // grid (16, 8)
    unsigned short* base = X2p + (size_t)b*NP*DIM;
    short8 z = {0,0,0,0,0,0,0,0};
    for (int task = part*256 + threadIdx.x; task < 10944; task += 2048) {
        int pos = task / 48, seg = task - pos*48;
        int py, px;
        if (pos < 58)       { py = 0;  px = pos; }
        else if (pos < 116) { py = 57; px = pos - 58; }
        else if (pos < 172) { py = pos - 115; px = 0; }
        else                { py = pos - 171; px = 57; }
        *(short8*)(base + ((size_t)(py*HP + px))*DIM + seg*8) = z;
    }
}

// ---------------- conv3x3 + BN + SiLU + residual, 4-wave acc[4][4] ----------------
// A-halo single-buffer + B tap-double-buffer, swizzled glds. forced 3 waves/SIMD.
__global__ __launch_bounds__(256, 3) void k_conv(
    const unsigned short* __restrict__ A, const unsigned short* __restrict__ Wt,
    const float* __restrict__ bn_g, const float* __restrict__ bn_b,
    const float* __restrict__ bn_mean, const float* __restrict__ bn_var,
    unsigned short* __restrict__ Yout)
{
    __shared__ __align__(16) char smem[32768];
    // k-loop: A halo [256][32] @0 (16KB), B dbuf 2x[128][32] @16384
    auto ctA = (float(*)[69])smem;                     // [64][69] 17664
    auto X2s = (unsigned short(*)[68])(smem + 17664);  // [64][68] 8704

    int bid = blockIdx.x;                 // 1200 = 8*150
    int orig = (bid & 7)*150 + (bid >> 3);
    int ct = orig % 3; int rest = orig / 3;
    int tile = rest % 25; int b = rest / 25;
    int n0 = tile*128, o0 = ct*128;
    int t = threadIdx.x;
    int wave = t >> 6, lane = t & 63;
    int wr = wave >> 1, wc = wave & 1;
    int lr = lane & 15, lg = lane >> 4;
    int qb = n0 + 2*(n0/56);
    const size_t bbase = (size_t)b*NP*DIM;

    int swcol = (((t & 3) ^ ((t >> 3) & 3)) << 3);
    // A-halo: 1024 tasks = 4/thread
    const unsigned short* asrc[4];
    #pragma unroll
    for (int j=0;j<4;j++) {
        int task = j*256 + t;
        int row = task >> 2;
        int q = qb + row; if (q > NP-1) q = NP-1;
        asrc[j] = A + bbase + (size_t)q*DIM + swcol;
    }
    // B: 512 tasks = 2/thread
    const unsigned short* bsrc0 = Wt + (size_t)(o0 + (t>>2))*3456 + swcol;
    const unsigned short* bsrc1 = Wt + (size_t)(o0 + 64 + (t>>2))*3456 + swcol;

    // per-lane MFMA A row offsets (position-relative)
    int qrel[4];
    #pragma unroll
    for (int i=0;i<4;i++) {
        int loc = wr*64 + i*16 + lr;
        int n = n0 + loc; if (n >= NN) n = NN-1;
        qrel[i] = n + 2*(n/56) - qb;
    }

    auto stageA = [&](int c) {
        #pragma unroll
        for (int j=0;j<4;j++) glds16(asrc[j] + c, smem + j*4096 + wave*1024);
    };
    auto stageB = [&](char* base, int off) {
        glds16(bsrc0 + off, base + wave*1024);
        glds16(bsrc1 + off, base + 4096 + wave*1024);
    };

    f32x4 acc[4][4];
    #pragma unroll
    for (int i=0;i<4;i++) for (int j=0;j<4;j++) acc[i][j] = (f32x4){0.f,0.f,0.f,0.f};

    stageA(0); stageB(smem + 16384, 0);
    __syncthreads();
    for (int kk = 0; kk < 12; kk++) {
        int c = kk*32;
        auto Ah = (unsigned short(*)[32])smem;
        #pragma unroll
        for (int tap = 0; tap < 9; tap++) {
            int buf = tap & 1;
            if (tap < 8) stageB(smem + 16384 + (buf^1)*8192, (tap+1)*384 + c);
            auto Bs = (unsigned short(*)[32])(smem + 16384 + buf*8192);
            int toff = (tap/3)*58 + (tap%3);
            short8 af[4], bfv[4];
            #pragma unroll
            for (int j=0;j<4;j++) {
                int brow = wc*64 + j*16 + lr;
                bfv[j] = *(short8*)&Bs[brow][(lg*8) ^ (((brow>>1)&3)<<3)];
            }
            #pragma unroll
            for (int i=0;i<4;i++) {
                int row = qrel[i] + toff;
                af[i] = *(short8*)&Ah[row][(lg*8) ^ (((row>>1)&3)<<3)];
            }
            #pragma unroll
            for (int i=0;i<4;i++)
                #pragma unroll
                for (int j=0;j<4;j++)
                    acc[i][j] = __builtin_amdgcn_mfma_f32_16x16x32_bf16(af[i], bfv[j], acc[i][j], 0, 0, 0);
            __syncthreads();
        }
        if (kk < 11) {
            stageA(c + 32);
            stageB(smem + 16384, c + 32);   // (kk+1, tap0) into buf0
            __syncthreads();
        }
    }

    // ---- epilogue: 4 quadrant passes (mh x oh), coalesced bf16 short8 writes ----
    for (int mh = 0; mh < 2; mh++) {
        for (int oh = 0; oh < 2; oh++) {
            __syncthreads();
            if (wr == mh && wc == oh) {
                #pragma unroll
                for (int i=0;i<4;i++) for (int j=0;j<4;j++) for (int r=0;r<4;r++)
                    ctA[j*16 + lr][i*16 + lg*4 + r] = acc[i][j][r];
            }
            for (int q = t; q < 512; q += 256) {    // residual: 64 m-rows x 8 o-segs(8)
                int row = q >> 3, sg = q & 7;
                int n = n0 + mh*64 + row; int nc = (n < NN) ? n : NN-1;
                int qq = nc + 2*(nc/56) + 59;       // center tap (+1,+1)
                short8 v = *(const short8*)(A + bbase + (size_t)qq*DIM + o0 + oh*64 + sg*8);
                short4v lo = {v[0],v[1],v[2],v[3]}, hi = {v[4],v[5],v[6],v[7]};
                *(short4v*)&X2s[row][sg*8]     = lo;
                *(short4v*)&X2s[row][sg*8 + 4] = hi;
            }
            __syncthreads();
            for (int q = t; q < 512; q += 256) {    // 64 o-rows x 8 n-segs(8)
                int orow = q >> 3, sg = q & 7;
                int o = o0 + oh*64 + orow;
                int n = n0 + mh*64 + sg*8;
                if (n < NN) {
                    float mean = bn_mean[o], rs = rsqrtf(bn_var[o] + 1e-5f);
                    float gg = bn_g[o], bb2 = bn_b[o];
                    unsigned short pk[8];
                    #pragma unroll
                    for (int e=0;e<8;e++) {
                        float xi = (ctA[orow][sg*8+e] - mean)*rs*gg + bb2;
                        float si = xi / (1.0f + __expf(-xi));
                        pk[e] = f2bf(si + bf2f(X2s[sg*8+e][orow]));
                    }
                    *(short8*)(Yout + ((size_t)(b*DIM + o))*NN + n) = *(short8*)pk;
                }
            }
        }
    }
}

// ---------------- attention stage 1: partial G = q k^T + partial sq-norms ----------------
__global__ __launch_bounds__(256) void k_qk(const unsigned short* __restrict__ Qb,
                                            const unsigned short* __restrict__ Kb,
                                            float* __restrict__ Gp, float* __restrict__ Np) {
    int cx = blockIdx.x, bh = blockIdx.y;
    int t = threadIdx.x, wave = t >> 6, lane = t & 63;
    int lr = lane & 15, lg = lane >> 4;
    {   // partial squared norms: 128 rows x 2 threads
        int row = t >> 1, p = t & 1;
        const unsigned short* src = (row < 64)
            ? Qb + ((size_t)bh*64 + row)*NN + cx*448
            : Kb + ((size_t)bh*64 + (row-64))*NN + cx*448;
        float s = 0.f;
        #pragma unroll
        for (int it = 0; it < 28; it++) {
            short8 v = *(const short8*)(src + p*224 + it*8);
            #pragma unroll
            for (int jj=0;jj<8;jj++) { float f = bf2f((unsigned short)v[jj]); s += f*f; }
        }
        s += __shfl_xor(s, 1, 64);
        if (p == 0) Np[((size_t)bh*7 + cx)*128 + row] = s;
    }
    f32x4 acc[4];
    #pragma unroll
    for (int j=0;j<4;j++) acc[j] = (f32x4){0.f,0.f,0.f,0.f};
    const unsigned short* qrow = Qb + ((size_t)bh*64 + wave*16 + lr)*NN + cx*448;
    const unsigned short* kbase = Kb + (size_t)bh*64*NN + cx*448;
    for (int ks = 0; ks < 14; ks++) {
        short8 a = *(const short8*)(qrow + ks*32 + lg*8);
        #pragma unroll
        for (int j=0;j<4;j++) {
            short8 bfr = *(const short8*)(kbase + (size_t)(j*16+lr)*NN + ks*32 + lg*8);
            acc[j] = __builtin_amdgcn_mfma_f32_16x16x32_bf16(a, bfr, acc[j], 0, 0, 0);
        }
    }
    float* gbase = Gp + ((size_t)bh*7 + cx)*4096;
    #pragma unroll
    for (int j=0;j<4;j++)
        #pragma unroll
        for (int r=0;r<4;r++)
            gbase[(wave*16 + lg*4 + r)*64 + j*16 + lr] = acc[j][r];
}

// ---------------- attention stage 2: combine + normalize + softmax -> ATT ----------------
__global__ __launch_bounds__(256) void k_sm(const float* __restrict__ Gp, const float* __restrict__ Np,
                                            const float* __restrict__ temperature,
                                            const float* __restrict__ rpb,
                                            unsigned short* __restrict__ ATT) {
    int bh = blockIdx.x; int h = bh % HEADS;
    int t = threadIdx.x;
    __shared__ float snorm[128];
    if (t < 128) {
        float s = 0.f;
        #pragma unroll
        for (int cx=0;cx<7;cx++) s += Np[((size_t)bh*7 + cx)*128 + t];
        snorm[t] = fmaxf(sqrtf(s), 1e-12f);
    }
    __syncthreads();
    int dq = t >> 2, de0 = (t & 3) * 16;
    f32x4 g[4];
    #pragma unroll
    for (int i=0;i<4;i++) g[i] = (f32x4){0.f,0.f,0.f,0.f};
    #pragma unroll
    for (int cx=0;cx<7;cx++) {
        const float* base = Gp + ((size_t)bh*7 + cx)*4096 + dq*64 + de0;
        #pragma unroll
        for (int i=0;i<4;i++) {
            float4 v = *(const float4*)(base + i*4);
            g[i][0]+=v.x; g[i][1]+=v.y; g[i][2]+=v.z; g[i][3]+=v.w;
        }
    }
    float temp = temperature[h];
    float bias = rpb[HEADS + h];
    float qn = snorm[dq];
    float lv[16]; float mx = -1e30f;
    #pragma unroll
    for (int i=0;i<4;i++)
        #pragma unroll
        for (int e=0;e<4;e++) {
            int de = de0 + i*4 + e;
            float v = g[i][e] / (qn * snorm[64 + de]) * temp + bias;
            lv[i*4+e] = v; mx = fmaxf(mx, v);
        }
    mx = fmaxf(mx, __shfl_xor(mx, 1, 64));
    mx = fmaxf(mx, __shfl_xor(mx, 2, 64));
    float se = 0.f;
    #pragma unroll
    for (int e=0;e<16;e++) { lv[e] = __expf(lv[e]-mx); se += lv[e]; }
    se += __shfl_xor(se, 1, 64);
    se += __shfl_xor(se, 2, 64);
    float inv = 1.0f/se;
    unsigned short pk[16];
    #pragma unroll
    for (int e=0;e<16;e++) pk[e] = f2bf(lv[e]*inv);
    unsigned short* dst = ATT + ((size_t)bh*64 + dq)*64 + de0;
    *(short8*)dst       = *(short8*)pk;
    *(short8*)(dst + 8) = *(short8*)(pk + 8);
}

// ---------------- PV: XCA[b][n][h*64+dd] = sum_e ATT[dd][e] * V[e][n] ----------------
__global__ __launch_bounds__(256) void k_pv(const unsigned short* __restrict__ ATT,
                                            const unsigned short* __restrict__ Vt,
                                            unsigned short* __restrict__ XCA) {
    int nt = blockIdx.x, bh = blockIdx.y;
    int b = bh / HEADS, h = bh % HEADS;
    int t = threadIdx.x, wave = t >> 6, lane = t & 63;
    int lr = lane & 15, lg = lane >> 4;
    int n0 = nt*64;
    __shared__ float ctP[64][67];
    f32x4 acc[4];
    for (int i=0;i<4;i++) acc[i] = (f32x4){0.f,0.f,0.f,0.f};
    for (int ks=0; ks<2; ks++) {
        short8 bfr = *reinterpret_cast<const short8*>(Vt + ((size_t)bh*NN + n0 + wave*16 + lr)*64 + ks*32 + lg*8);
        for (int i=0;i<4;i++) {
            short8 a = *reinterpret_cast<const short8*>(ATT + ((size_t)bh*64 + i*16 + lr)*64 + ks*32 + lg*8);
            acc[i] = __builtin_amdgcn_mfma_f32_16x16x32_bf16(a, bfr, acc[i], 0, 0, 0);
        }
    }
    int nl = wave*16 + lr;
    #pragma unroll
    for (int i=0;i<4;i++)
        #pragma unroll
        for (int r=0;r<4;r++) ctP[nl][i*16 + lg*4 + r] = acc[i][r];
    __syncthreads();
    for (int q = t; q < 512; q += 256) {   // 64 n-rows x 8 dd-segs(8)
        int row = q >> 3, seg = q & 7;
        unsigned short pk[8];
        #pragma unroll
        for (int e=0;e<8;e++) pk[e] = f2bf(ctP[row][seg*8+e]);
        *(short8*)(XCA + ((size_t)(b*NN + n0 + row))*DIM + h*64 + seg*8) = *(short8*)pk;
    }
}

// ---------------- final: out = x + gamma-shuffled residual (Y bf16) ----------------
__global__ __launch_bounds__(256) void k_final(const float* __restrict__ x, const unsigned short* __restrict__ Yb,
                                               const float* __restrict__ gamma, float* __restrict__ out) {
    int i = blockIdx.x, b = blockIdx.y, kc = blockIdx.z;
    __shared__ float tile[56*193];
    int t = threadIdx.x;
    int k0 = kc*192;
    const unsigned short* ybase = Yb + (size_t)b*DIM*NN + (size_t)i*21504 + k0;
    for (int q = t; q < 56*24; q += 256) {
        int j = q / 24, c8 = (q % 24) * 8;
        short8 v = *(const short8*)(ybase + (size_t)j*384 + c8);
        float* dst = &tile[j*193 + c8];
        #pragma unroll
        for (int e=0;e<8;e++) dst[e] = bf2f((unsigned short)v[e]);
    }
    __syncthreads();
    for (int q = t; q < 192*56; q += 256) {
        int kl = q / 56, j = q % 56;
        int k = k0 + kl;
        size_t gi = ((size_t)(b*DIM + k))*NN + (size_t)i*56 + j;
        out[gi] = x[gi] + gamma[k] * tile[j*193 + kl];
    }
}

extern "C" void kernel_launch(void* const* d_in, const int* in_sizes, int n_in,
                              void* d_out, int out_size, void* d_ws, size_t ws_size,
                              hipStream_t stream) {
    const float* x       = (const float*)d_in[0];
    const float* pos_w   = (const float*)d_in[1];
    const float* pos_b   = (const float*)d_in[2];
    const float* ln_g    = (const float*)d_in[3];
    const float* ln_b    = (const float*)d_in[4];
    const float* gxca    = (const float*)d_in[5];
    const float* temp    = (const float*)d_in[6];
    const float* qkv_w   = (const float*)d_in[7];
    const float* qkv_b   = (const float*)d_in[8];
    const float* proj_w  = (const float*)d_in[9];
    const float* proj_b  = (const float*)d_in[10];
    const float* rpb     = (const float*)d_in[11];
    const float* conv_w  = (const float*)d_in[12];
    const float* bn_g    = (const float*)d_in[13];
    const float* bn_b    = (const float*)d_in[14];
    const float* bn_mean = (const float*)d_in[15];
    const float* bn_var  = (const float*)d_in[16];
    const float* gamma   = (const float*)d_in[17];
    float* out = (float*)d_out;
    char* ws = (char*)d_ws;

    const size_t oP   = 0;                        // P: 4,816,896 B
    const size_t oXT  = oP   + 4816896;           // XTb bf16 38.5MB (reused as Y bf16 after proj)
    const size_t oXN  = oXT  + 77070336;          // XN bf16: 38,535,168 B   (reused as Gp/Np, then XCA)
    const size_t oQ   = oXN  + 38535168;          // Qb bf16                  (reused as X2p padded, spans into Kb)
    const size_t oK   = oQ   + 38535168;          // Kb bf16
    const size_t oV   = oK   + 38535168;          // Vt bf16
    const size_t oATT = oV   + 38535168;          // ATT bf16: 786,432 B
    const size_t oWq  = oATT + 786432;            // 884,736 B
    const size_t oWp  = oWq  + 884736;            // 294,912 B
    const size_t oWc  = oWp  + 294912;            // 2,654,208 B

    float* P            = (float*)(ws + oP);
    unsigned short* XTb = (unsigned short*)(ws + oXT);
    unsigned short* Yb  = (unsigned short*)(ws + oXT);  // alias (XTb dead after proj epilogue)
    unsigned short* XN  = (unsigned short*)(ws + oXN);
    float* Gp           = (float*)(ws + oXN);               // alias (XN dead after qkv GEMM)
    float* Np           = (float*)(ws + oXN + 11010048);
    unsigned short* XCA = (unsigned short*)(ws + oXN);      // alias (Gp/Np dead after k_sm)
    unsigned short* Qb  = (unsigned short*)(ws + oQ);
    unsigned short* X2p = (unsigned short*)(ws + oQ);   // alias (Qb+Kb dead after k_qk)
    unsigned short* Kb  = (unsigned short*)(ws + oK);
    unsigned short* Vt  = (unsigned short*)(ws + oV);
    unsigned short* ATT = (unsigned short*)(ws + oATT);
    unsigned short* Wq  = (unsigned short*)(ws + oWq);
    unsigned short* Wp  = (unsigned short*)(ws + oWp);
    unsigned short* Wc  = (unsigned short*)(ws + oWc);

    kw_convert<<<256, 256, 0, stream>>>(qkv_w, proj_w, conv_w, Wq, Wp, Wc);
    k_pos<<<NN, 128, 0, stream>>>(pos_w, pos_b, P);
    k_tln<<<BB*98, 256, 0, stream>>>(x, P, ln_g, ln_b, XTb, XN);
    k_gemm<0><<<3528, 256, 0, stream>>>(XN, Wq, qkv_b,
        Qb, Kb, Vt, nullptr, nullptr, nullptr);
    k_qk<<<dim3(7, BH), 256, 0, stream>>>(Qb, Kb, Gp, Np);
    k_sm<<<BH, 256, 0, stream>>>(Gp, Np, temp, rpb, ATT);
    k_pad<<<dim3(BB, 8), 256, 0, stream>>>(X2p);
    k_pv<<<dim3(49, BH), 256, 0, stream>>>(ATT, Vt, XCA);
    k_gemm<1><<<1176, 256, 0, stream>>>(XCA, Wp, proj_b,
        nullptr, nullptr, nullptr, XTb, gxca, X2p);
    k_conv<<<1200, 256, 0, stream>>>(X2p, Wc, bn_g, bn_b, bn_mean, bn_var, Yb);
    k_final<<<dim3(56, BB, 2), 256, 0, stream>>>(x, Yb, gamma, out);
}

// Round 8
// 459.786 us; speedup vs baseline: 1.6806x; 1.0311x over previous
//
#include <hip/hip_runtime.h>
#include <hip/hip_bf16.h>
#include <math.h>

#define DIM 384
#define HEADS 6
#define NN 3136
#define BB 16
#define BH (BB*HEADS)
#define HP 58
#define NP (HP*HP)   // 3364 padded image

typedef __attribute__((ext_vector_type(8))) short short8;
typedef __attribute__((ext_vector_type(4))) short short4v;
typedef __attribute__((ext_vector_type(4))) float f32x4;

__device__ __forceinline__ float bf2f(unsigned short u) {
    union { unsigned int i; float f; } v; v.i = ((unsigned int)u) << 16; return v.f;
}
__device__ __forceinline__ unsigned short f2bf(float f) {
    union { float f; unsigned int i; } v; v.f = f;
    unsigned int r = v.i + 0x7fffu + ((v.i >> 16) & 1u);
    return (unsigned short)(r >> 16);
}
__device__ __forceinline__ void glds16(const unsigned short* g, void* l) {
    __builtin_amdgcn_global_load_lds(
        (const __attribute__((address_space(1))) unsigned int*)g,
        (__attribute__((address_space(3))) unsigned int*)l, 16, 0, 0);
}

// ---------------- weight conversion / rearrange ----------------
__global__ void kw_convert(const float* __restrict__ qkv_w, const float* __restrict__ proj_w,
                           const float* __restrict__ conv_w,
                           unsigned short* __restrict__ Wq, unsigned short* __restrict__ Wp,
                           unsigned short* __restrict__ Wc) {
    int tid = blockIdx.x * 256 + threadIdx.x;
    int stride = gridDim.x * 256;
    for (int i = tid; i < 3*DIM*DIM; i += stride) Wq[i] = f2bf(qkv_w[i]);
    for (int i = tid; i < DIM*DIM; i += stride) Wp[i] = f2bf(proj_w[i]);
    for (int i = tid; i < DIM*DIM*9; i += stride) {
        // dst layout: [o][tap][i]   src: (o, i, ky, kx) -> (o*384+i)*9 + tap
        int ii = i % DIM; int rest = i / DIM; int tap = rest % 9; int o = rest / 9;
        Wc[i] = f2bf(conv_w[(size_t)(o*DIM + ii)*9 + tap]);
    }
}

// ---------------- positional encoding table P[n][c] ----------------
__global__ void k_pos(const float* __restrict__ pos_w, const float* __restrict__ pos_b,
                      float* __restrict__ P) {
    int n = blockIdx.x; int h = n / 56, w = n % 56;
    __shared__ float feat[64];
    int t = threadIdx.x;
    if (t < 64) {
        int axis = t >> 5;      // 0 = y (h), 1 = x (w)
        int k = t & 31; int i = k >> 1;
        float e = (float)((axis ? w : h) + 1) / 56.000001f * 6.28318530717958647692f;
        float arg = e / powf(10000.0f, (float)i / 16.0f);
        feat[t] = (k & 1) ? cosf(arg) : sinf(arg);
    }
    __syncthreads();
    for (int c = t; c < DIM; c += blockDim.x) {
        float s = pos_b[c];
        #pragma unroll 8
        for (int k = 0; k < 64; k++) s += feat[k] * pos_w[c*64 + k];
        P[(size_t)n*DIM + c] = s;
    }
}

// ---------------- fused transpose + pos add + layernorm ----------------
__global__ __launch_bounds__(256) void k_tln(const float* __restrict__ x, const float* __restrict__ P,
                                             const float* __restrict__ g, const float* __restrict__ be,
                                             unsigned short* __restrict__ XTb, unsigned short* __restrict__ XN) {
    __shared__ float tile[32][388];
    int blk = blockIdx.x;
    int b = blk / 98, nt = blk % 98;
    int n0 = nt*32;
    int t = threadIdx.x;
    #pragma unroll
    for (int it = 0; it < 12; it++) {
        int task = it*256 + t;
        int c = task >> 3, seg = task & 7;
        float4 v = *reinterpret_cast<const float4*>(x + ((size_t)(b*DIM + c))*NN + n0 + seg*4);
        tile[seg*4+0][c] = v.x; tile[seg*4+1][c] = v.y;
        tile[seg*4+2][c] = v.z; tile[seg*4+3][c] = v.w;
    }
    __syncthreads();
    int row = t >> 3, sub = t & 7;
    int n = n0 + row;
    f32x4 xp[12];
    float s = 0.f;
    #pragma unroll
    for (int k = 0; k < 12; k++) {
        int c0 = (k*8 + sub)*4;
        float4 tv = *reinterpret_cast<float4*>(&tile[row][c0]);
        float4 pv = *reinterpret_cast<const float4*>(P + (size_t)n*DIM + c0);
        f32x4 xv = {tv.x+pv.x, tv.y+pv.y, tv.z+pv.z, tv.w+pv.w};
        xp[k] = xv;
        s += xv[0]+xv[1]+xv[2]+xv[3];
        unsigned short pkx[4];
        #pragma unroll
        for (int e=0;e<4;e++) pkx[e] = f2bf(xv[e]);
        *reinterpret_cast<short4v*>(XTb + ((size_t)(b*NN + n))*DIM + c0) = *(short4v*)pkx;
    }
    s += __shfl_xor(s, 1, 64); s += __shfl_xor(s, 2, 64); s += __shfl_xor(s, 4, 64);
    float mean = s * (1.0f/384.0f);
    float sq = 0.f;
    #pragma unroll
    for (int k = 0; k < 12; k++) {
        #pragma unroll
        for (int e = 0; e < 4; e++) { float d = xp[k][e]-mean; sq += d*d; }
    }
    sq += __shfl_xor(sq, 1, 64); sq += __shfl_xor(sq, 2, 64); sq += __shfl_xor(sq, 4, 64);
    float rs = rsqrtf(sq * (1.0f/384.0f) + 1e-6f);
    #pragma unroll
    for (int k = 0; k < 12; k++) {
        int c0 = (k*8 + sub)*4;
        unsigned short pk[4];
        #pragma unroll
        for (int e = 0; e < 4; e++)
            pk[e] = f2bf((xp[k][e]-mean)*rs*g[c0+e] + be[c0+e]);
        *reinterpret_cast<short4v*>(XN + ((size_t)(b*NN + n))*DIM + c0) = *(short4v*)pk;
    }
}

// ---------------- MFMA GEMM (K=384): MODE 0 = qkv, 1 = proj ----------------
// A+B dbuf via swizzled global_load_lds; counted-vmcnt raw barriers (T4).
template<int MODE>
__global__ __launch_bounds__(256) void k_gemm(
    const unsigned short* __restrict__ A, const unsigned short* __restrict__ Wt,
    const float* __restrict__ bias,
    unsigned short* __restrict__ Qb, unsigned short* __restrict__ Kb, unsigned short* __restrict__ Vt,
    const unsigned short* __restrict__ XTb, const float* __restrict__ gxca, unsigned short* __restrict__ X2p)
{
    __shared__ __align__(16) char smem[35328];
    auto ctA = (float(*)[69])smem;                     // [128][69] 35328  ([o][m])
    auto ctB = (float(*)[130])smem;                    // [64][130] 33280  ([m][o])

    constexpr int NCT = (MODE == 0) ? 9 : 3;
    constexpr int CPX = (MODE == 0) ? 441 : 147;       // 392*NCT/8
    int bid = blockIdx.x;
    int orig = (bid & 7)*CPX + (bid >> 3);
    int ct = orig % NCT, mt = orig / NCT;
    int m0 = mt*128, o0 = ct*128;
    int t = threadIdx.x;
    int wave = t >> 6, lane = t & 63;
    int wr = wave >> 1, wc = wave & 1;
    int lr = lane & 15, lg = lane >> 4;

    // staging: source col pre-swizzled (both-sides rule for global_load_lds)
    int r0 = t >> 2;
    int swcol = (((t & 3) ^ ((t >> 3) & 3)) << 3);
    const unsigned short* a0 = A  + (size_t)(m0 + r0)*384 + swcol;
    const unsigned short* a1 = A  + (size_t)(m0 + 64 + r0)*384 + swcol;
    const unsigned short* b0 = Wt + (size_t)(o0 + r0)*384 + swcol;
    const unsigned short* b1 = Wt + (size_t)(o0 + 64 + r0)*384 + swcol;
    int rsw = ((lr >> 1) & 3) << 3;    // read-side swizzle (shorts)

    auto stage = [&](char* base, int c) {
        glds16(a0 + c, base + wave*1024);
        glds16(a1 + c, base + 4096 + wave*1024);
        glds16(b0 + c, base + 8192 + wave*1024);
        glds16(b1 + c, base + 12288 + wave*1024);
    };

    f32x4 acc[4][4];
    #pragma unroll
    for (int i=0;i<4;i++) for (int j=0;j<4;j++) acc[i][j] = (f32x4){0.f,0.f,0.f,0.f};

    stage(smem, 0);
    for (int kk = 0; kk < 12; kk++) {
        if (kk < 11) {
            stage(smem + ((kk+1)&1)*16384, (kk+1)*32);
            asm volatile("s_waitcnt vmcnt(4)" ::: "memory");
        } else {
            asm volatile("s_waitcnt vmcnt(0)" ::: "memory");
        }
        __builtin_amdgcn_s_barrier();
        __builtin_amdgcn_sched_barrier(0);
        auto As = (unsigned short(*)[32])(smem + (kk&1)*16384);
        auto Bs = (unsigned short(*)[32])(smem + (kk&1)*16384 + 8192);
        short8 af[4], bfv[4];
        #pragma unroll
        for (int i=0;i<4;i++) af[i]  = *(short8*)&As[wr*64 + i*16 + lr][(lg*8) ^ rsw];
        #pragma unroll
        for (int j=0;j<4;j++) bfv[j] = *(short8*)&Bs[wc*64 + j*16 + lr][(lg*8) ^ rsw];
        #pragma unroll
        for (int i=0;i<4;i++)
            #pragma unroll
            for (int j=0;j<4;j++)
                acc[i][j] = __builtin_amdgcn_mfma_f32_16x16x32_bf16(af[i], bfv[j], acc[i][j], 0, 0, 0);
        __builtin_amdgcn_s_barrier();
        __builtin_amdgcn_sched_barrier(0);
    }

    // ---- epilogue ----
    int comp = (MODE == 0) ? (o0 / DIM) : 0;
    for (int mh = 0; mh < 2; mh++) {
        __syncthreads();
        bool useB = (MODE == 1) || (MODE == 0 && comp == 2);
        if (wr == mh) {
            if (useB) {
                #pragma unroll
                for (int i=0;i<4;i++) for (int j=0;j<4;j++) for (int r=0;r<4;r++)
                    ctB[i*16 + lg*4 + r][wc*64 + j*16 + lr] = acc[i][j][r];
            } else {
                #pragma unroll
                for (int i=0;i<4;i++) for (int j=0;j<4;j++) for (int r=0;r<4;r++)
                    ctA[wc*64 + j*16 + lr][i*16 + lg*4 + r] = acc[i][j][r];
            }
        }
        __syncthreads();
        if (MODE == 1) {
            for (int q = t; q < 1024; q += 256) {   // 64 m-rows x 16 o-segs(8)
                int row = q >> 4, seg = q & 15;
                int m = m0 + mh*64 + row; int b = m/NN; int n = m - b*NN;
                int py = n/56, px = n - py*56;
                int og0 = o0 + seg*8;
                short8 xvb = *(const short8*)(XTb + (size_t)m*DIM + og0);
                unsigned short pk[8];
                #pragma unroll
                for (int e=0;e<8;e++) {
                    float val = ctB[row][seg*8+e] + bias[og0+e];
                    pk[e] = f2bf(bf2f((unsigned short)xvb[e]) + gxca[og0+e]*val);
                }
                *(short8*)(X2p + ((size_t)(b*NP + (py+1)*HP + px + 1))*DIM + og0) = *(short8*)pk;
            }
        } else if (comp < 2) {                      // Q / K: (bh,dd,N) layout
            unsigned short* Dst = (comp == 0) ? Qb : Kb;
            for (int q = t; q < 2048; q += 256) {   // 128 o-rows x 16 m-segs(4)
                int row = q >> 4, seg = q & 15;
                int og = o0 + row; int rem = og - comp*DIM;
                int hh = rem >> 6, dd = rem & 63;
                int m4 = m0 + mh*64 + seg*4; int b = m4/NN; int n = m4 - b*NN;
                float bv = bias[og];
                unsigned short pk[4];
                #pragma unroll
                for (int e=0;e<4;e++) pk[e] = f2bf(ctA[row][seg*4+e] + bv);
                *(short4v*)(Dst + ((size_t)((b*HEADS + hh)*64 + dd))*NN + n) = *(short4v*)pk;
            }
        } else {                                    // V: (bh,N,dd) layout
            for (int q = t; q < 1024; q += 256) {   // 64 m-rows x 16 o-segs(8)
                int row = q >> 4, seg = q & 15;
                int m = m0 + mh*64 + row; int b = m/NN; int n = m - b*NN;
                int og0 = o0 + seg*8; int rem0 = og0 - 2*DIM;
                int hh = rem0 >> 6, dd0 = rem0 & 63;
                unsigned short pk[8];
                #pragma unroll
                for (int e=0;e<8;e++) pk[e] = f2bf(ctB[row][seg*8+e] + bias[og0+e]);
                *(short8*)(Vt + ((size_t)((b*HEADS + hh)*NN + n))*64 + dd0) = *(short8*)pk;
            }
        }
    }
}

// ---------------- pad-ring zero for X2p ----------------
__global__ __launch_bounds__(256) void k_pad(unsigned short* __restrict__ X2p) {
    int b = blockIdx.x, part = blockIdx.y;   // grid (16, 8)
    unsigned short* base = X2p + (size_t)b*NP*DIM;
    short8 z = {0,0,0,0,0,0,0,0};
    for (int task = part*256 + threadIdx.x; task < 10944; task += 2048) {
        int pos = task / 48, seg = task - pos*48;
        int py, px;
        if (pos < 58)       { py = 0;  px = pos; }
        else if (pos < 116) { py = 57; px = pos - 58; }
        else if (pos < 172) { py = pos - 115; px = 0; }
        else                { py = pos - 171; px = 57; }
        *(short8*)(base + ((size_t)(py*HP + px))*DIM + seg*8) = z;
    }
}

// ---------------- conv3x3 + BN + SiLU + residual, counted-vmcnt pipeline ----------------
// A-halo DOUBLE buffer (staged at tap 6 of prev kk) + B dbuf; raw barriers + counted vmcnt.
__global__ __launch_bounds__(256, 3) void k_conv(
    const unsigned short* __restrict__ A, const unsigned short* __restrict__ Wt,
    const float* __restrict__ bn_g, const float* __restrict__ bn_b,
    const float* __restrict__ bn_mean, const float* __restrict__ bn_var,
    unsigned short* __restrict__ Yout)
{
    __shared__ __align__(16) char smem[49152];
    // k-loop: A halo dbuf 2x[256][32] @0 (32KB), B dbuf 2x[128][32] @32768 (16KB)
    auto ctA = (float(*)[69])smem;                     // epilogue alias [64][69] 17664
    auto X2s = (unsigned short(*)[68])(smem + 17664);  // [64][68] 8704

    int bid = blockIdx.x;                 // 1200 = 8*150
    int orig = (bid & 7)*150 + (bid >> 3);
    int ct = orig % 3; int rest = orig / 3;
    int tile = rest % 25; int b = rest / 25;
    int n0 = tile*128, o0 = ct*128;
    int t = threadIdx.x;
    int wave = t >> 6, lane = t & 63;
    int wr = wave >> 1, wc = wave & 1;
    int lr = lane & 15, lg = lane >> 4;
    int qb = n0 + 2*(n0/56);
    const size_t bbase = (size_t)b*NP*DIM;

    int swcol = (((t & 3) ^ ((t >> 3) & 3)) << 3);
    // A-halo: 1024 tasks = 4/thread
    const unsigned short* asrc[4];
    #pragma unroll
    for (int j=0;j<4;j++) {
        int task = j*256 + t;
        int row = task >> 2;
        int q = qb + row; if (q > NP-1) q = NP-1;
        asrc[j] = A + bbase + (size_t)q*DIM + swcol;
    }
    // B: 512 tasks = 2/thread
    const unsigned short* bsrc0 = Wt + (size_t)(o0 + (t>>2))*3456 + swcol;
    const unsigned short* bsrc1 = Wt + (size_t)(o0 + 64 + (t>>2))*3456 + swcol;

    // per-lane MFMA A row offsets (position-relative)
    int qrel[4];
    #pragma unroll
    for (int i=0;i<4;i++) {
        int loc = wr*64 + i*16 + lr;
        int n = n0 + loc; if (n >= NN) n = NN-1;
        qrel[i] = n + 2*(n/56) - qb;
    }

    auto stageA = [&](int bufsel, int c) {
        #pragma unroll
        for (int j=0;j<4;j++) glds16(asrc[j] + c, smem + bufsel*16384 + j*4096 + wave*1024);
    };
    auto stageB = [&](int slot, int off) {
        glds16(bsrc0 + off, smem + 32768 + slot*8192 + wave*1024);
        glds16(bsrc1 + off, smem + 32768 + slot*8192 + 4096 + wave*1024);
    };

    f32x4 acc[4][4];
    #pragma unroll
    for (int i=0;i<4;i++) for (int j=0;j<4;j++) acc[i][j] = (f32x4){0.f,0.f,0.f,0.f};

    stageA(0, 0); stageB(0, 0);
    for (int kk = 0; kk < 12; kk++) {
        auto Ah = (unsigned short(*)[32])(smem + (kk&1)*16384);
        #pragma unroll
        for (int tap = 0; tap < 9; tap++) {
            // issue next-tap B (slot for step s+1)
            if (kk < 11 || tap < 8) {
                int off = (tap < 8) ? ((tap+1)*384 + kk*32) : ((kk+1)*32);
                stageB((kk+tap+1)&1, off);
            }
            if (tap == 6 && kk < 11) stageA((kk+1)&1, (kk+1)*32);
            // counted waits: B(s) must be landed; keep later loads in flight
            if (kk < 11 && (tap == 6 || tap == 7))
                asm volatile("s_waitcnt vmcnt(6)" ::: "memory");
            else if (kk == 11 && tap == 8)
                asm volatile("s_waitcnt vmcnt(0)" ::: "memory");
            else
                asm volatile("s_waitcnt vmcnt(2)" ::: "memory");
            __builtin_amdgcn_s_barrier();
            __builtin_amdgcn_sched_barrier(0);
            auto Bs = (unsigned short(*)[32])(smem + 32768 + ((kk+tap)&1)*8192);
            int toff = (tap/3)*58 + (tap%3);
            short8 af[4], bfv[4];
            #pragma unroll
            for (int j=0;j<4;j++) {
                int brow = wc*64 + j*16 + lr;
                bfv[j] = *(short8*)&Bs[brow][(lg*8) ^ (((brow>>1)&3)<<3)];
            }
            #pragma unroll
            for (int i=0;i<4;i++) {
                int row = qrel[i] + toff;
                af[i] = *(short8*)&Ah[row][(lg*8) ^ (((row>>1)&3)<<3)];
            }
            #pragma unroll
            for (int i=0;i<4;i++)
                #pragma unroll
                for (int j=0;j<4;j++)
                    acc[i][j] = __builtin_amdgcn_mfma_f32_16x16x32_bf16(af[i], bfv[j], acc[i][j], 0, 0, 0);
            __builtin_amdgcn_s_barrier();
            __builtin_amdgcn_sched_barrier(0);
        }
    }

    // ---- epilogue: 4 quadrant passes (mh x oh), coalesced bf16 short8 writes ----
    for (int mh = 0; mh < 2; mh++) {
        for (int oh = 0; oh < 2; oh++) {
            __syncthreads();
            if (wr == mh && wc == oh) {
                #pragma unroll
                for (int i=0;i<4;i++) for (int j=0;j<4;j++) for (int r=0;r<4;r++)
                    ctA[j*16 + lr][i*16 + lg*4 + r] = acc[i][j][r];
            }
            for (int q = t; q < 512; q += 256) {    // residual: 64 m-rows x 8 o-segs(8)
                int row = q >> 3, sg = q & 7;
                int n = n0 + mh*64 + row; int nc = (n < NN) ? n : NN-1;
                int qq = nc + 2*(nc/56) + 59;       // center tap (+1,+1)
                short8 v = *(const short8*)(A + bbase + (size_t)qq*DIM + o0 + oh*64 + sg*8);
                short4v lo = {v[0],v[1],v[2],v[3]}, hi = {v[4],v[5],v[6],v[7]};
                *(short4v*)&X2s[row][sg*8]     = lo;
                *(short4v*)&X2s[row][sg*8 + 4] = hi;
            }
            __syncthreads();
            for (int q = t; q < 512; q += 256) {    // 64 o-rows x 8 n-segs(8)
                int orow = q >> 3, sg = q & 7;
                int o = o0 + oh*64 + orow;
                int n = n0 + mh*64 + sg*8;
                if (n < NN) {
                    float mean = bn_mean[o], rs = rsqrtf(bn_var[o] + 1e-5f);
                    float gg = bn_g[o], bb2 = bn_b[o];
                    unsigned short pk[8];
                    #pragma unroll
                    for (int e=0;e<8;e++) {
                        float xi = (ctA[orow][sg*8+e] - mean)*rs*gg + bb2;
                        float si = xi / (1.0f + __expf(-xi));
                        pk[e] = f2bf(si + bf2f(X2s[sg*8+e][orow]));
                    }
                    *(short8*)(Yout + ((size_t)(b*DIM + o))*NN + n) = *(short8*)pk;
                }
            }
        }
    }
}

// ---------------- attention stage 1: partial G = q k^T + partial sq-norms ----------------
__global__ __launch_bounds__(256) void k_qk(const unsigned short* __restrict__ Qb,
                                            const unsigned short* __restrict__ Kb,
                                            float* __restrict__ Gp, float* __restrict__ Np) {
    int cx = blockIdx.x, bh = blockIdx.y;
    int t = threadIdx.x, wave = t >> 6, lane = t & 63;
    int lr = lane & 15, lg = lane >> 4;
    {   // partial squared norms: 128 rows x 2 threads
        int row = t >> 1, p = t & 1;
        const unsigned short* src = (row < 64)
            ? Qb + ((size_t)bh*64 + row)*NN + cx*448
            : Kb + ((size_t)bh*64 + (row-64))*NN + cx*448;
        float s = 0.f;
        #pragma unroll
        for (int it = 0; it < 28; it++) {
            short8 v = *(const short8*)(src + p*224 + it*8);
            #pragma unroll
            for (int jj=0;jj<8;jj++) { float f = bf2f((unsigned short)v[jj]); s += f*f; }
        }
        s += __shfl_xor(s, 1, 64);
        if (p == 0) Np[((size_t)bh*7 + cx)*128 + row] = s;
    }
    f32x4 acc[4];
    #pragma unroll
    for (int j=0;j<4;j++) acc[j] = (f32x4){0.f,0.f,0.f,0.f};
    const unsigned short* qrow = Qb + ((size_t)bh*64 + wave*16 + lr)*NN + cx*448;
    const unsigned short* kbase = Kb + (size_t)bh*64*NN + cx*448;
    for (int ks = 0; ks < 14; ks++) {
        short8 a = *(const short8*)(qrow + ks*32 + lg*8);
        #pragma unroll
        for (int j=0;j<4;j++) {
            short8 bfr = *(const short8*)(kbase + (size_t)(j*16+lr)*NN + ks*32 + lg*8);
            acc[j] = __builtin_amdgcn_mfma_f32_16x16x32_bf16(a, bfr, acc[j], 0, 0, 0);
        }
    }
    float* gbase = Gp + ((size_t)bh*7 + cx)*4096;
    #pragma unroll
    for (int j=0;j<4;j++)
        #pragma unroll
        for (int r=0;r<4;r++)
            gbase[(wave*16 + lg*4 + r)*64 + j*16 + lr] = acc[j][r];
}

// ---------------- attention stage 2: combine + normalize + softmax -> ATT ----------------
__global__ __launch_bounds__(256) void k_sm(const float* __restrict__ Gp, const float* __restrict__ Np,
                                            const float* __restrict__ temperature,
                                            const float* __restrict__ rpb,
                                            unsigned short* __restrict__ ATT) {
    int bh = blockIdx.x; int h = bh % HEADS;
    int t = threadIdx.x;
    __shared__ float snorm[128];
    if (t < 128) {
        float s = 0.f;
        #pragma unroll
        for (int cx=0;cx<7;cx++) s += Np[((size_t)bh*7 + cx)*128 + t];
        snorm[t] = fmaxf(sqrtf(s), 1e-12f);
    }
    __syncthreads();
    int dq = t >> 2, de0 = (t & 3) * 16;
    f32x4 g[4];
    #pragma unroll
    for (int i=0;i<4;i++) g[i] = (f32x4){0.f,0.f,0.f,0.f};
    #pragma unroll
    for (int cx=0;cx<7;cx++) {
        const float* base = Gp + ((size_t)bh*7 + cx)*4096 + dq*64 + de0;
        #pragma unroll
        for (int i=0;i<4;i++) {
            float4 v = *(const float4*)(base + i*4);
            g[i][0]+=v.x; g[i][1]+=v.y; g[i][2]+=v.z; g[i][3]+=v.w;
        }
    }
    float temp = temperature[h];
    float bias = rpb[HEADS + h];
    float qn = snorm[dq];
    float lv[16]; float mx = -1e30f;
    #pragma unroll
    for (int i=0;i<4;i++)
        #pragma unroll
        for (int e=0;e<4;e++) {
            int de = de0 + i*4 + e;
            float v = g[i][e] / (qn * snorm[64 + de]) * temp + bias;
            lv[i*4+e] = v; mx = fmaxf(mx, v);
        }
    mx = fmaxf(mx, __shfl_xor(mx, 1, 64));
    mx = fmaxf(mx, __shfl_xor(mx, 2, 64));
    float se = 0.f;
    #pragma unroll
    for (int e=0;e<16;e++) { lv[e] = __expf(lv[e]-mx); se += lv[e]; }
    se += __shfl_xor(se, 1, 64);
    se += __shfl_xor(se, 2, 64);
    float inv = 1.0f/se;
    unsigned short pk[16];
    #pragma unroll
    for (int e=0;e<16;e++) pk[e] = f2bf(lv[e]*inv);
    unsigned short* dst = ATT + ((size_t)bh*64 + dq)*64 + de0;
    *(short8*)dst       = *(short8*)pk;
    *(short8*)(dst + 8) = *(short8*)(pk + 8);
}

// ---------------- PV: XCA[b][n][h*64+dd] = sum_e ATT[dd][e] * V[e][n] ----------------
__global__ __launch_bounds__(256) void k_pv(const unsigned short* __restrict__ ATT,
                                            const unsigned short* __restrict__ Vt,
                                            unsigned short* __restrict__ XCA) {
    int nt = blockIdx.x, bh = blockIdx.y;
    int b = bh / HEADS, h = bh % HEADS;
    int t = threadIdx.x, wave = t >> 6, lane = t & 63;
    int lr = lane & 15, lg = lane >> 4;
    int n0 = nt*64;
    __shared__ float ctP[64][67];
    f32x4 acc[4];
    for (int i=0;i<4;i++) acc[i] = (f32x4){0.f,0.f,0.f,0.f};
    for (int ks=0; ks<2; ks++) {
        short8 bfr = *reinterpret_cast<const short8*>(Vt + ((size_t)bh*NN + n0 + wave*16 + lr)*64 + ks*32 + lg*8);
        for (int i=0;i<4;i++) {
            short8 a = *reinterpret_cast<const short8*>(ATT + ((size_t)bh*64 + i*16 + lr)*64 + ks*32 + lg*8);
            acc[i] = __builtin_amdgcn_mfma_f32_16x16x32_bf16(a, bfr, acc[i], 0, 0, 0);
        }
    }
    int nl = wave*16 + lr;
    #pragma unroll
    for (int i=0;i<4;i++)
        #pragma unroll
        for (int r=0;r<4;r++) ctP[nl][i*16 + lg*4 + r] = acc[i][r];
    __syncthreads();
    for (int q = t; q < 512; q += 256) {   // 64 n-rows x 8 dd-segs(8)
        int row = q >> 3, seg = q & 7;
        unsigned short pk[8];
        #pragma unroll
        for (int e=0;e<8;e++) pk[e] = f2bf(ctP[row][seg*8+e]);
        *(short8*)(XCA + ((size_t)(b*NN + n0 + row))*DIM + h*64 + seg*8) = *(short8*)pk;
    }
}

// ---------------- final: out = x + gamma-shuffled residual (Y bf16) ----------------
__global__ __launch_bounds__(256) void k_final(const float* __restrict__ x, const unsigned short* __restrict__ Yb,
                                               const float* __restrict__ gamma, float* __restrict__ out) {
    int i = blockIdx.x, b = blockIdx.y, kc = blockIdx.z;
    __shared__ float tile[56*193];
    int t = threadIdx.x;
    int k0 = kc*192;
    const unsigned short* ybase = Yb + (size_t)b*DIM*NN + (size_t)i*21504 + k0;
    for (int q = t; q < 56*24; q += 256) {
        int j = q / 24, c8 = (q % 24) * 8;
        short8 v = *(const short8*)(ybase + (size_t)j*384 + c8);
        float* dst = &tile[j*193 + c8];
        #pragma unroll
        for (int e=0;e<8;e++) dst[e] = bf2f((unsigned short)v[e]);
    }
    __syncthreads();
    for (int q = t; q < 192*56; q += 256) {
        int kl = q / 56, j = q % 56;
        int k = k0 + kl;
        size_t gi = ((size_t)(b*DIM + k))*NN + (size_t)i*56 + j;
        out[gi] = x[gi] + gamma[k] * tile[j*193 + kl];
    }
}

extern "C" void kernel_launch(void* const* d_in, const int* in_sizes, int n_in,
                              void* d_out, int out_size, void* d_ws, size_t ws_size,
                              hipStream_t stream) {
    const float* x       = (const float*)d_in[0];
    const float* pos_w   = (const float*)d_in[1];
    const float* pos_b   = (const float*)d_in[2];
    const float* ln_g    = (const float*)d_in[3];
    const float* ln_b    = (const float*)d_in[4];
    const float* gxca    = (const float*)d_in[5];
    const float* temp    = (const float*)d_in[6];
    const float* qkv_w   = (const float*)d_in[7];
    const float* qkv_b   = (const float*)d_in[8];
    const float* proj_w  = (const float*)d_in[9];
    const float* proj_b  = (const float*)d_in[10];
    const float* rpb     = (const float*)d_in[11];
    const float* conv_w  = (const float*)d_in[12];
    const float* bn_g    = (const float*)d_in[13];
    const float* bn_b    = (const float*)d_in[14];
    const float* bn_mean = (const float*)d_in[15];
    const float* bn_var  = (const float*)d_in[16];
    const float* gamma   = (const float*)d_in[17];
    float* out = (float*)d_out;
    char* ws = (char*)d_ws;

    const size_t oP   = 0;                        // P: 4,816,896 B
    const size_t oXT  = oP   + 4816896;           // XTb bf16 38.5MB (reused as Y bf16 after proj)
    const size_t oXN  = oXT  + 77070336;          // XN bf16: 38,535,168 B   (reused as Gp/Np, then XCA)
    const size_t oQ   = oXN  + 38535168;          // Qb bf16                  (reused as X2p padded, spans into Kb)
    const size_t oK   = oQ   + 38535168;          // Kb bf16
    const size_t oV   = oK   + 38535168;          // Vt bf16
    const size_t oATT = oV   + 38535168;          // ATT bf16: 786,432 B
    const size_t oWq  = oATT + 786432;            // 884,736 B
    const size_t oWp  = oWq  + 884736;            // 294,912 B
    const size_t oWc  = oWp  + 294912;            // 2,654,208 B

    float* P            = (float*)(ws + oP);
    unsigned short* XTb = (unsigned short*)(ws + oXT);
    unsigned short* Yb  = (unsigned short*)(ws + oXT);  // alias (XTb dead after proj epilogue)
    unsigned short* XN  = (unsigned short*)(ws + oXN);
    float* Gp           = (float*)(ws + oXN);               // alias (XN dead after qkv GEMM)
    float* Np           = (float*)(ws + oXN + 11010048);
    unsigned short* XCA = (unsigned short*)(ws + oXN);      // alias (Gp/Np dead after k_sm)
    unsigned short* Qb  = (unsigned short*)(ws + oQ);
    unsigned short* X2p = (unsigned short*)(ws + oQ);   // alias (Qb+Kb dead after k_qk)
    unsigned short* Kb  = (unsigned short*)(ws + oK);
    unsigned short* Vt  = (unsigned short*)(ws + oV);
    unsigned short* ATT = (unsigned short*)(ws + oATT);
    unsigned short* Wq  = (unsigned short*)(ws + oWq);
    unsigned short* Wp  = (unsigned short*)(ws + oWp);
    unsigned short* Wc  = (unsigned short*)(ws + oWc);

    kw_convert<<<256, 256, 0, stream>>>(qkv_w, proj_w, conv_w, Wq, Wp, Wc);
    k_pos<<<NN, 128, 0, stream>>>(pos_w, pos_b, P);
    k_tln<<<BB*98, 256, 0, stream>>>(x, P, ln_g, ln_b, XTb, XN);
    k_gemm<0><<<3528, 256, 0, stream>>>(XN, Wq, qkv_b,
        Qb, Kb, Vt, nullptr, nullptr, nullptr);
    k_qk<<<dim3(7, BH), 256, 0, stream>>>(Qb, Kb, Gp, Np);
    k_sm<<<BH, 256, 0, stream>>>(Gp, Np, temp, rpb, ATT);
    k_pad<<<dim3(BB, 8), 256, 0, stream>>>(X2p);
    k_pv<<<dim3(49, BH), 256, 0, stream>>>(ATT, Vt, XCA);
    k_gemm<1><<<1176, 256, 0, stream>>>(XCA, Wp, proj_b,
        nullptr, nullptr, nullptr, XTb, gxca, X2p);
    k_conv<<<1200, 256, 0, stream>>>(X2p, Wc, bn_g, bn_b, bn_mean, bn_var, Yb);
    k_final<<<dim3(56, BB, 2), 256, 0, stream>>>(x, Yb, gamma, out);
}